// Round 1
// baseline (2894.049 us; speedup 1.0000x reference)
//
#include <hip/hip_runtime.h>

typedef unsigned short u16;
typedef unsigned int   u32;
typedef unsigned long long u64;
typedef __attribute__((ext_vector_type(8))) short short8;
typedef __attribute__((ext_vector_type(4))) float f32x4;

#define DEV static __device__ __forceinline__

DEV float bf2f(u16 u){ return __uint_as_float(((u32)u)<<16); }
DEV u16 f2bf(float f){ u32 u=__float_as_uint(f); return (u16)((u + 0x7FFFu + ((u>>16)&1u))>>16); }
DEV float sigf(float x){ return 1.f/(1.f+__expf(-x)); }
DEV float tanhfast(float x){ return 2.f*sigf(2.f*x)-1.f; }

// float -> OCP e4m3fn (RNE-ish, saturating)
DEV unsigned char f2e4m3(float x){
  u32 u = __float_as_uint(x);
  u32 s = (u>>31)<<7;
  u &= 0x7FFFFFFFu;
  if (u >= 0x43DC0000u) return (unsigned char)(s|0x7E);   // >=440 -> sat 448
  if (u <  0x3A800000u) return (unsigned char)s;          // < 2^-10 -> 0
  u32 ur = u + 0x00080000u;                               // round into top-3 mantissa
  int expn = (int)(ur>>23) - 127;
  u32 man = (ur>>20)&7u;
  if (expn < -6){                                         // subnormal: unit 2^-9
    float ax = __uint_as_float(u);
    int q = (int)rintf(ax*512.f);
    if (q>=8) return (unsigned char)(s|0x08);
    return (unsigned char)(s|(u32)q);
  }
  return (unsigned char)(s | ((u32)(expn+7)<<3) | man);
}

// ---------------- prep kernels ----------------

// cgate_tab[c][g] = char_emb[c]@cWi + cb   (128 x 512 f32)
__global__ void prep_cgate(const float* __restrict__ emb, const float* __restrict__ cWi,
                           const float* __restrict__ cb, float* __restrict__ tab){
  int c = blockIdx.x;
  for (int g = threadIdx.x; g < 512; g += 256){
    float sacc = cb[g];
    for (int k=0;k<64;k++) sacc += emb[c*64+k]*cWi[k*512+g];
    tab[c*512+g]=sacc;
  }
}

// pack main-LSTM recurrent weights fp8, frag-major: [dir][w8][tt8][ks8][lane64] u64
__global__ void pack_whq(const float* __restrict__ fWh, const float* __restrict__ bWh,
                         u64* __restrict__ whq){
  int blk = blockIdx.x;            // 1024
  int l = threadIdx.x;             // 64
  int ks = blk&7, tt=(blk>>3)&7, w=(blk>>6)&7, dir=blk>>9;
  const float* W = dir? bWh : fWh;
  int col = 256*(tt>>1) + 32*w + 16*(tt&1) + (l&15);
  u64 v=0;
  for (int j=0;j<8;j++){
    int k = ks*32 + ((l>>4)&3)*8 + j;
    unsigned char q = f2e4m3(W[(size_t)k*1024+col]*8.f);
    v |= ((u64)q)<<(8*j);
  }
  whq[(size_t)blk*64 + l] = v;
}

// pack char-LSTM recurrent weights bf16, frag-major: [w8][tt4][ks4][lane64] 8xbf16
__global__ void pack_whc(const float* __restrict__ cWh, u16* __restrict__ whc){
  int blk=blockIdx.x;              // 128
  int l=threadIdx.x;
  int ks=blk&3, tt=(blk>>2)&3, w=blk>>4;
  int col = 128*tt + 16*w + (l&15);
  u16 vals[8];
  for (int j=0;j<8;j++){
    int k = ks*32 + ((l>>4)&3)*8 + j;
    vals[j] = f2bf(cWh[(size_t)k*512+col]);
  }
  *((uint4*)whc + (size_t)blk*64 + l) = *(uint4*)vals;
}

// generic bf16 B-fragment pack: dst[(ks*(N/16)+n)*64+l] = 8 bf16 (k-consecutive)
// mode 0: Wi concat (fWi|bWi), K=512 (pad from 492); mode 1: conv taps; mode 2: bilin concat
__global__ void pack_bfrag(const float* __restrict__ S0, const float* __restrict__ S1,
                           u16* __restrict__ dst, int N, int K, int mode){
  int blk = blockIdx.x; int l = threadIdx.x;
  int Nt = N>>4;
  int ks = blk / Nt, n = blk % Nt;
  int col = n*16 + (l&15);
  u16 vals[8];
  for (int j=0;j<8;j++){
    int k = ks*32 + ((l>>4)&3)*8 + j;
    float v;
    if (mode==0){
      v = (k<492) ? (col<1024 ? S0[(size_t)k*1024+col] : S1[(size_t)k*1024+col-1024]) : 0.f;
    } else if (mode==1){
      int tap=k>>9, kk=k&511;
      v = (col<512) ? S0[((size_t)tap*512+kk)*512+col] : S1[((size_t)tap*512+kk)*512+col-512];
    } else {
      v = (col<512) ? S0[(size_t)k*512+col] : S1[(size_t)k*512+col-512];
    }
    vals[j]=f2bf(v);
  }
  *((uint4*)dst + (size_t)blk*64 + l) = *(uint4*)vals;
}

// word/pos embedding gather into xpad[8192][512] bf16 (cols 0..300, 300..364; zero 492..512)
__global__ void embed_gather(const int* __restrict__ words, const int* __restrict__ poss,
                             const float* __restrict__ wemb, const float* __restrict__ pemb,
                             u16* __restrict__ xpad){
  int row = blockIdx.x; int tid = threadIdx.x;   // 128 threads
  int wd = words[row], ps = poss[row];
  const float* wsrc = wemb + (size_t)wd*300;
  u16* xr = xpad + (size_t)row*512;
  for (int i=tid;i<300;i+=128) xr[i] = f2bf(wsrc[i]);
  if (tid<64) xr[300+tid] = f2bf(pemb[(size_t)ps*64+tid]);
  if (tid>=108) xr[492 + (tid-108)] = 0;
}

// ---------------- char LSTM ----------------
// 512 blocks x 512 thr (8 waves). Block handles 16 rows; wave w owns units [16w,16w+16).
__global__ __launch_bounds__(512) void char_lstm(
  const u16* __restrict__ whcf, const float* __restrict__ cgate,
  const int* __restrict__ chars, const int* __restrict__ char_len,
  u16* __restrict__ xpad){
  const int tid = threadIdx.x; const int l = tid&63, w = tid>>6;
  const int rbase = blockIdx.x*16;
  __shared__ u16 hlds[16][136];   // 272B stride (16B aligned)
  __shared__ int chs[16][16];
  __shared__ int cidx[16];
  for (int i = tid; i < 16*136; i += 512) ((u16*)hlds)[i] = 0;
  if (tid < 256) chs[tid>>4][tid&15] = chars[(size_t)(rbase + (tid>>4))*16 + (tid&15)];
  if (tid < 16){ int cl = char_len[rbase+tid]-1; cidx[tid] = cl<0?0:(cl>15?15:cl); }
  short8 bq[4][4];
  #pragma unroll
  for (int tt=0;tt<4;tt++)
    #pragma unroll
    for(int ks=0;ks<4;ks++)
      bq[tt][ks] = *((const short8*)whcf + (((w*4+tt)*4+ks)*64 + l));
  float c[4] = {0.f,0.f,0.f,0.f};
  const int u = w*16 + (l&15);
  __syncthreads();
  for (int s=0;s<16;s++){
    short8 a[4];
    #pragma unroll
    for (int ks=0;ks<4;ks++)
      a[ks] = *(const short8*)&hlds[l&15][ks*32 + ((l>>4)&3)*8];
    f32x4 acc[4];
    f32x4 zf4 = {0.f,0.f,0.f,0.f};
    #pragma unroll
    for (int tt=0;tt<4;tt++) acc[tt]=zf4;
    #pragma unroll
    for (int tt=0;tt<4;tt++)
      #pragma unroll
      for (int ks=0;ks<4;ks++)
        acc[tt] = __builtin_amdgcn_mfma_f32_16x16x32_bf16(a[ks], bq[tt][ks], acc[tt],0,0,0);
    float hv[4];
    #pragma unroll
    for (int q=0;q<4;q++){
      int r = ((l>>4)&3)*4 + q;
      int ch = chs[r][s];
      const float* tb = cgate + (size_t)ch*512 + u;
      float zi = tb[0]   + acc[0][q];
      float zf = tb[128] + acc[1][q];
      float zg = tb[256] + acc[2][q];
      float zo = tb[384] + acc[3][q];
      float cn = sigf(zf)*c[q] + sigf(zi)*tanhfast(zg);
      c[q] = cn;
      hv[q] = sigf(zo)*tanhfast(cn);
    }
    __syncthreads();
    #pragma unroll
    for (int q=0;q<4;q++){
      int r = ((l>>4)&3)*4 + q;
      u16 hb = f2bf(hv[q]);
      hlds[r][u] = hb;
      if (s == cidx[r]) xpad[(size_t)(rbase + r)*512 + 364 + u] = hb;
    }
    __syncthreads();
  }
}

// ---------------- main LSTM (fwd/bwd), one WG per direction ----------------
// 2 blocks x 512 thr (8 waves). fp8 register-resident Wh (x8), h quantized fp8 (x4).
__global__ __launch_bounds__(512,2) void main_lstm(
  const u64* __restrict__ whq, const u16* __restrict__ xmain,
  const int* __restrict__ seq_len, u16* __restrict__ hidden){
  const int dir = blockIdx.x;
  const int tid = threadIdx.x; const int l = tid&63, w = tid>>6;
  __shared__ unsigned char hlds[16][272];
  __shared__ int sl[16];
  for (int i=tid; i<16*272; i+=512) ((unsigned char*)hlds)[i]=0;
  if (tid<16) sl[tid] = seq_len[tid];
  u64 bq[8][8];
  #pragma unroll
  for (int tt=0;tt<8;tt++)
    #pragma unroll
    for(int ks=0;ks<8;ks++)
      bq[tt][ks] = whq[ (((size_t)(dir*8+w)*8+tt)*8+ks)*64 + l ];
  float c[2][4] = {{0.f,0.f,0.f,0.f},{0.f,0.f,0.f,0.f}};
  __syncthreads();
  for (int t=0;t<512;t++){
    u64 a[8];
    #pragma unroll
    for (int ks=0;ks<8;ks++)
      a[ks] = *(const u64*)&hlds[l&15][ks*32 + ((l>>4)&3)*8];
    // X loads (independent of recurrence) issued before MFMA block
    const u16* xb = xmain + ((size_t)(dir*512+t)*16)*1024;
    u16 xv[2][4][4];
    #pragma unroll
    for (int hh=0;hh<2;hh++)
      #pragma unroll
      for (int q=0;q<4;q++){
        int r = ((l>>4)&3)*4+q; int u = w*32 + hh*16 + (l&15);
        const u16* xr = xb + r*1024 + u;
        xv[hh][q][0]=xr[0]; xv[hh][q][1]=xr[256]; xv[hh][q][2]=xr[512]; xv[hh][q][3]=xr[768];
      }
    f32x4 acc[8];
    f32x4 zf4 = {0.f,0.f,0.f,0.f};
    #pragma unroll
    for (int tt=0;tt<8;tt++) acc[tt]=zf4;
    #pragma unroll
    for (int tt=0;tt<8;tt++)
      #pragma unroll
      for (int ks=0;ks<8;ks++)
        acc[tt] = __builtin_amdgcn_mfma_f32_16x16x32_fp8_fp8((long)a[ks], (long)bq[tt][ks], acc[tt],0,0,0);
    int t_src = dir? (511-t) : t;
    float hv[2][4];
    #pragma unroll
    for (int hh=0;hh<2;hh++)
      #pragma unroll
      for (int q=0;q<4;q++){
        float zi = bf2f(xv[hh][q][0]) + acc[0+hh][q]*(1.f/32.f);
        float zf = bf2f(xv[hh][q][1]) + acc[2+hh][q]*(1.f/32.f);
        float zg = bf2f(xv[hh][q][2]) + acc[4+hh][q]*(1.f/32.f);
        float zo = bf2f(xv[hh][q][3]) + acc[6+hh][q]*(1.f/32.f);
        float cn = sigf(zf)*c[hh][q] + sigf(zi)*tanhfast(zg);
        c[hh][q]=cn;
        hv[hh][q] = sigf(zo)*tanhfast(cn);
      }
    __syncthreads();
    #pragma unroll
    for (int hh=0;hh<2;hh++)
      #pragma unroll
      for (int q=0;q<4;q++){
        int r=((l>>4)&3)*4+q; int u = w*32+hh*16+(l&15);
        hlds[r][u] = f2e4m3(hv[hh][q]*4.f);
        float hm = (t_src < sl[r]) ? hv[hh][q] : 0.f;
        hidden[((size_t)r*512 + t_src)*512 + dir*256 + u] = f2bf(hm);
      }
    __syncthreads();
  }
}

// ---------------- generic MFMA GEMM (A row-major bf16, B frag-packed) ----------------
// 256 thr = 4 waves; wave: 16 rows x 128 cols. mode 0: ->Xmain(+bias, time-reorder)
// mode 1: conv (A from hidden with t-1/t taps) -> relu -> flfr ; mode 2: -> ulur
__global__ __launch_bounds__(256) void gemm_frag(
    const u16* __restrict__ A, const u16* __restrict__ Bf,
    int N, int K, int mode,
    const float* __restrict__ bias0, const float* __restrict__ bias1,
    u16* __restrict__ out, const u16* __restrict__ hid){
  const int tid = threadIdx.x;
  const int l = tid & 63, w = tid >> 6;
  const int row0 = blockIdx.x*64 + w*16;
  const int col0 = blockIdx.y*128;
  const int Nt16 = N>>4;
  f32x4 acc[8];
  f32x4 zf4 = {0.f,0.f,0.f,0.f};
  #pragma unroll
  for (int i=0;i<8;i++) acc[i]=zf4;
  const int rl = row0 + (l&15);
  const int kb = ((l>>4)&3)*8;
  const int nK = K>>5;
  for (int ks=0; ks<nK; ++ks){
    int kc = ks*32 + kb;
    short8 a;
    if (mode==1){
      int b = rl>>9, t = rl&511;
      if (kc < 512){
        if (t==0){ short8 z8={0,0,0,0,0,0,0,0}; a=z8; }
        else a = *(const short8*)(hid + ((size_t)(b*512 + t-1)*512 + kc));
      } else {
        a = *(const short8*)(hid + ((size_t)(b*512 + t)*512 + (kc-512)));
      }
    } else {
      a = *(const short8*)(A + ((size_t)rl*K + kc));
    }
    const short8* bp = (const short8*)Bf + ((size_t)ks*Nt16 + (col0>>4))*64 + l;
    #pragma unroll
    for (int n=0;n<8;n++){
      short8 b8 = bp[n*64];
      acc[n] = __builtin_amdgcn_mfma_f32_16x16x32_bf16(a, b8, acc[n], 0,0,0);
    }
  }
  #pragma unroll
  for (int n=0;n<8;n++){
    int col = col0 + n*16 + (l&15);
    #pragma unroll
    for (int q=0;q<4;q++){
      int row = row0 + ((l>>4)&3)*4 + q;
      float v = acc[n][q];
      if (mode==0){
        int d = col>>10, g = col&1023;
        v += d ? bias1[g] : bias0[g];
        int b = row>>9, t = row&511;
        int t2 = d ? (511-t) : t;
        out[(((size_t)d*512 + t2)*16 + b)*1024 + g] = f2bf(v);
      } else if (mode==1){
        v += (col<512)? bias0[col] : bias1[col-512];
        v = fmaxf(v, 0.f);
        out[(size_t)row*1024 + col] = f2bf(v);
      } else {
        out[(size_t)row*1024 + col] = f2bf(v);
      }
    }
  }
}

// ---------------- ll/lr ----------------
__global__ __launch_bounds__(256) void lin_kernel(const u16* __restrict__ flfr,
    const float* __restrict__ lw, const float* __restrict__ lb,
    const float* __restrict__ rw, const float* __restrict__ rb,
    float* __restrict__ llr){
  int row = blockIdx.x*4 + (threadIdx.x>>6);
  int l = threadIdx.x&63;
  const u16* fr = flfr + (size_t)row*1024;
  float pl=0.f, pr=0.f;
  #pragma unroll
  for (int j=0;j<8;j++){
    int ci = l*8+j;
    pl += bf2f(fr[ci]) * lw[ci];
    pr += bf2f(fr[512+ci]) * rw[ci];
  }
  #pragma unroll
  for (int off=32; off; off>>=1){ pl += __shfl_xor(pl, off, 64); pr += __shfl_xor(pr, off, 64); }
  if (l==0){ llr[row] = pl + lb[0]; llr[8192+row] = pr + rb[0]; }
}

// ---------------- banded bilinear + softmax ----------------
__global__ __launch_bounds__(256) void band_softmax(
  const u16* __restrict__ ulur, const u16* __restrict__ flfr,
  const float* __restrict__ llr, float* __restrict__ outp){
  int row = blockIdx.x*4 + (threadIdx.x>>6);
  int l = threadIdx.x&63;
  int b = row>>9, i = row&511;
  float ul[8], ur[8];
  const u16* up = ulur + (size_t)row*1024;
  #pragma unroll
  for (int j=0;j<8;j++){ ul[j]=bf2f(up[l*8+j]); ur[j]=bf2f(up[512+l*8+j]); }
  float sL = -1e30f, sR = -1e30f;
  for (int idx=0; idx<16; ++idx){
    int jL = i - idx;
    float p = 0.f;
    if (jL >= 0){
      const u16* f = flfr + (size_t)(b*512+jL)*1024;
      #pragma unroll
      for (int j=0;j<8;j++) p += ul[j]*bf2f(f[l*8+j]);
    }
    #pragma unroll
    for (int off=32; off; off>>=1) p += __shfl_xor(p, off, 64);
    if (l==idx && jL>=0) sL = p + llr[b*512+jL];
    int jR = i + idx;
    float pr_ = 0.f;
    if (jR < 512){
      const u16* f = flfr + (size_t)(b*512+jR)*1024;
      #pragma unroll
      for (int j=0;j<8;j++) pr_ += ur[j]*bf2f(f[512+l*8+j]);
    }
    #pragma unroll
    for (int off=32; off; off>>=1) pr_ += __shfl_xor(pr_, off, 64);
    if (l==idx && jR<512) sR = pr_ + llr[8192+b*512+jR];
  }
  // softmax over lanes 0..15 (groups of 16); lanes>=16 produce unused NaN/0
  float mL = sL, mR = sR;
  #pragma unroll
  for (int off=8; off; off>>=1){ mL = fmaxf(mL, __shfl_xor(mL, off, 16)); mR = fmaxf(mR, __shfl_xor(mR, off, 16)); }
  float eL = (sL>-1e29f)? __expf(sL-mL) : 0.f;
  float eR = (sR>-1e29f)? __expf(sR-mR) : 0.f;
  float suL = eL, suR = eR;
  #pragma unroll
  for (int off=8; off; off>>=1){ suL += __shfl_xor(suL, off, 16); suR += __shfl_xor(suR, off, 16); }
  float pL = eL/suL, pR = eR/suR;
  size_t obase = ((size_t)b*512 + i)*512;
  float vl[8], vr[8];
  #pragma unroll
  for (int j=0;j<8;j++){
    int ci = l*8+j;
    int ixl = i - ci;
    float v1 = __shfl(pL, ixl & 15, 64);
    vl[j] = (ixl>=0 && ixl<16) ? v1 : 0.f;
    int ixr = ci - i;
    float v2 = __shfl(pR, ixr & 15, 64);
    vr[j] = (ixr>=0 && ixr<16) ? v2 : 0.f;
  }
  float4* oL = (float4*)(outp + obase + l*8);
  oL[0] = make_float4(vl[0],vl[1],vl[2],vl[3]);
  oL[1] = make_float4(vl[4],vl[5],vl[6],vl[7]);
  float4* oR = (float4*)(outp + (size_t)16*512*512 + obase + l*8);
  oR[0] = make_float4(vr[0],vr[1],vr[2],vr[3]);
  oR[1] = make_float4(vr[4],vr[5],vr[6],vr[7]);
}

// ---------------- host launch ----------------
extern "C" void kernel_launch(void* const* d_in, const int* in_sizes, int n_in,
                              void* d_out, int out_size, void* d_ws, size_t ws_size,
                              hipStream_t stream) {
  const int* words    = (const int*)d_in[0];
  const int* poss     = (const int*)d_in[1];
  const int* seq_len  = (const int*)d_in[2];
  const int* chars    = (const int*)d_in[3];
  const int* char_len = (const int*)d_in[4];
  const float* word_emb = (const float*)d_in[6];
  const float* pos_emb  = (const float*)d_in[7];
  const float* char_emb = (const float*)d_in[8];
  const float* cWi = (const float*)d_in[9];
  const float* cWh = (const float*)d_in[10];
  const float* cb  = (const float*)d_in[11];
  const float* fWi = (const float*)d_in[12];
  const float* fWh = (const float*)d_in[13];
  const float* fb  = (const float*)d_in[14];
  const float* bWi = (const float*)d_in[15];
  const float* bWh = (const float*)d_in[16];
  const float* bb  = (const float*)d_in[17];
  const float* convL_k = (const float*)d_in[18];
  const float* convL_b = (const float*)d_in[19];
  const float* convR_k = (const float*)d_in[20];
  const float* convR_b = (const float*)d_in[21];
  const float* bilinL  = (const float*)d_in[22];
  const float* bilinR  = (const float*)d_in[23];
  const float* linL_w  = (const float*)d_in[24];
  const float* linL_b  = (const float*)d_in[25];
  const float* linR_w  = (const float*)d_in[26];
  const float* linR_b  = (const float*)d_in[27];

  char* ws = (char*)d_ws;
  constexpr size_t OFF_WHQ = 0;
  constexpr size_t OFF_WHC = OFF_WHQ + 524288;
  constexpr size_t OFF_WIF = OFF_WHC + 131072;
  constexpr size_t OFF_CVF = OFF_WIF + 2097152;
  constexpr size_t OFF_BLF = OFF_CVF + 2097152;
  constexpr size_t OFF_CGT = OFF_BLF + 1048576;
  constexpr size_t OFF_XPD = OFF_CGT + 262144;
  constexpr size_t OFF_XMN = OFF_XPD + 8388608;
  constexpr size_t OFF_HID = OFF_XMN + 33554432;
  constexpr size_t OFF_FLR = OFF_HID + 8388608;
  constexpr size_t OFF_ULR = OFF_FLR + 16777216;
  constexpr size_t OFF_LLR = OFF_ULR + 16777216;

  pack_whq<<<1024,64,0,stream>>>(fWh,bWh,(u64*)(ws+OFF_WHQ));
  pack_whc<<<128,64,0,stream>>>(cWh,(u16*)(ws+OFF_WHC));
  pack_bfrag<<<2048,64,0,stream>>>(fWi,bWi,(u16*)(ws+OFF_WIF),2048,512,0);
  pack_bfrag<<<2048,64,0,stream>>>(convL_k,convR_k,(u16*)(ws+OFF_CVF),1024,1024,1);
  pack_bfrag<<<1024,64,0,stream>>>(bilinL,bilinR,(u16*)(ws+OFF_BLF),1024,512,2);
  prep_cgate<<<128,256,0,stream>>>(char_emb,cWi,cb,(float*)(ws+OFF_CGT));
  embed_gather<<<8192,128,0,stream>>>(words,poss,word_emb,pos_emb,(u16*)(ws+OFF_XPD));
  char_lstm<<<512,512,0,stream>>>((const u16*)(ws+OFF_WHC),(const float*)(ws+OFF_CGT),
                                  chars,char_len,(u16*)(ws+OFF_XPD));
  gemm_frag<<<dim3(128,16),256,0,stream>>>((const u16*)(ws+OFF_XPD),(const u16*)(ws+OFF_WIF),
                                  2048,512,0,fb,bb,(u16*)(ws+OFF_XMN),nullptr);
  main_lstm<<<2,512,0,stream>>>((const u64*)(ws+OFF_WHQ),(const u16*)(ws+OFF_XMN),
                                  seq_len,(u16*)(ws+OFF_HID));
  gemm_frag<<<dim3(128,8),256,0,stream>>>(nullptr,(const u16*)(ws+OFF_CVF),
                                  1024,1024,1,convL_b,convR_b,(u16*)(ws+OFF_FLR),(const u16*)(ws+OFF_HID));
  gemm_frag<<<dim3(128,8),256,0,stream>>>((const u16*)(ws+OFF_HID),(const u16*)(ws+OFF_BLF),
                                  1024,512,2,convL_b,convR_b,(u16*)(ws+OFF_ULR),nullptr);
  lin_kernel<<<2048,256,0,stream>>>((const u16*)(ws+OFF_FLR),linL_w,linL_b,linR_w,linR_b,
                                  (float*)(ws+OFF_LLR));
  band_softmax<<<2048,256,0,stream>>>((const u16*)(ws+OFF_ULR),(const u16*)(ws+OFF_FLR),
                                  (const float*)(ws+OFF_LLR),(float*)d_out);
}

// Round 3
// 2458.932 us; speedup vs baseline: 1.1770x; 1.1770x over previous
//
#include <hip/hip_runtime.h>

typedef unsigned short u16;
typedef unsigned int   u32;
typedef unsigned long long u64;
typedef __attribute__((ext_vector_type(8))) short short8;
typedef __attribute__((ext_vector_type(4))) float f32x4;

#define DEV static __device__ __forceinline__

DEV float bf2f(u16 u){ return __uint_as_float(((u32)u)<<16); }
DEV u16 f2bf(float f){ u32 u=__float_as_uint(f); return (u16)((u + 0x7FFFu + ((u>>16)&1u))>>16); }
DEV float sigf(float x){ return 1.f/(1.f+__expf(-x)); }
DEV float tanhfast(float x){ return 2.f*sigf(2.f*x)-1.f; }

// float -> OCP e4m3fn (host-prep only; hot path uses v_cvt_pk_fp8_f32)
DEV unsigned char f2e4m3(float x){
  u32 u = __float_as_uint(x);
  u32 s = (u>>31)<<7;
  u &= 0x7FFFFFFFu;
  if (u >= 0x43DC0000u) return (unsigned char)(s|0x7E);
  if (u <  0x3A800000u) return (unsigned char)s;
  u32 ur = u + 0x00080000u;
  int expn = (int)(ur>>23) - 127;
  u32 man = (ur>>20)&7u;
  if (expn < -6){
    float ax = __uint_as_float(u);
    int q = (int)rintf(ax*512.f);
    if (q>=8) return (unsigned char)(s|0x08);
    return (unsigned char)(s|(u32)q);
  }
  return (unsigned char)(s | ((u32)(expn+7)<<3) | man);
}

// ---------------- prep kernels ----------------

__global__ void prep_cgate(const float* __restrict__ emb, const float* __restrict__ cWi,
                           const float* __restrict__ cb, float* __restrict__ tab){
  int c = blockIdx.x;
  for (int g = threadIdx.x; g < 512; g += 256){
    float sacc = cb[g];
    for (int k=0;k<64;k++) sacc += emb[c*64+k]*cWi[k*512+g];
    tab[c*512+g]=sacc;
  }
}

// pack main-LSTM recurrent weights fp8 x8, frag-major: [dir][w8][tt8][ks8][lane64] u64
// tt = gate*2 + parity; tile cols: u = w*32 + 2*(l&15) + p ; src col = gate*256 + u
__global__ void pack_whq(const float* __restrict__ fWh, const float* __restrict__ bWh,
                         u64* __restrict__ whq){
  int blk = blockIdx.x;            // 1024
  int l = threadIdx.x;             // 64
  int ks = blk&7, tt=(blk>>3)&7, w=(blk>>6)&7, dir=blk>>9;
  const float* W = dir? bWh : fWh;
  int col = (tt>>1)*256 + w*32 + 2*(l&15) + (tt&1);
  u64 v=0;
  for (int j=0;j<8;j++){
    int k = ks*32 + ((l>>4)&3)*8 + j;
    unsigned char q = f2e4m3(W[(size_t)k*1024+col]*8.f);
    v |= ((u64)q)<<(8*j);
  }
  whq[(size_t)blk*64 + l] = v;
}

// pack char-LSTM recurrent weights bf16, frag-major: [w8][tt4][ks4][lane64] 8xbf16
__global__ void pack_whc(const float* __restrict__ cWh, u16* __restrict__ whc){
  int blk=blockIdx.x;              // 128
  int l=threadIdx.x;
  int ks=blk&3, tt=(blk>>2)&3, w=blk>>4;
  int col = 128*tt + 16*w + (l&15);
  u16 vals[8];
  for (int j=0;j<8;j++){
    int k = ks*32 + ((l>>4)&3)*8 + j;
    vals[j] = f2bf(cWh[(size_t)k*512+col]);
  }
  *((uint4*)whc + (size_t)blk*64 + l) = *(uint4*)vals;
}

// generic bf16 B-fragment pack: dst[(ks*(N/16)+n)*64+l] = 8 bf16 (k-consecutive)
// mode 0: Wi concat (fWi|bWi), K=512 (pad from 492), cols gate-interleaved: c1=u*4+gate
// mode 1: conv taps; mode 2: bilin concat
__global__ void pack_bfrag(const float* __restrict__ S0, const float* __restrict__ S1,
                           u16* __restrict__ dst, int N, int K, int mode){
  int blk = blockIdx.x; int l = threadIdx.x;
  int Nt = N>>4;
  int ks = blk / Nt, n = blk % Nt;
  int col = n*16 + (l&15);
  u16 vals[8];
  for (int j=0;j<8;j++){
    int k = ks*32 + ((l>>4)&3)*8 + j;
    float v;
    if (mode==0){
      int d = col>>10, c1 = col&1023;
      int srccol = (c1&3)*256 + (c1>>2);
      v = (k<492) ? (d ? S1[(size_t)k*1024+srccol] : S0[(size_t)k*1024+srccol]) : 0.f;
    } else if (mode==1){
      int tap=k>>9, kk=k&511;
      v = (col<512) ? S0[((size_t)tap*512+kk)*512+col] : S1[((size_t)tap*512+kk)*512+col-512];
    } else {
      v = (col<512) ? S0[(size_t)k*512+col] : S1[(size_t)k*512+col-512];
    }
    vals[j]=f2bf(v);
  }
  *((uint4*)dst + (size_t)blk*64 + l) = *(uint4*)vals;
}

// word/pos embedding gather into xpad[8192][512] bf16
__global__ void embed_gather(const int* __restrict__ words, const int* __restrict__ poss,
                             const float* __restrict__ wemb, const float* __restrict__ pemb,
                             u16* __restrict__ xpad){
  int row = blockIdx.x; int tid = threadIdx.x;   // 128 threads
  int wd = words[row], ps = poss[row];
  const float* wsrc = wemb + (size_t)wd*300;
  u16* xr = xpad + (size_t)row*512;
  for (int i=tid;i<300;i+=128) xr[i] = f2bf(wsrc[i]);
  if (tid<64) xr[300+tid] = f2bf(pemb[(size_t)ps*64+tid]);
  if (tid>=108) xr[492 + (tid-108)] = 0;
}

// ---------------- char LSTM ----------------
__global__ __launch_bounds__(512) void char_lstm(
  const u16* __restrict__ whcf, const float* __restrict__ cgate,
  const int* __restrict__ chars, const int* __restrict__ char_len,
  u16* __restrict__ xpad){
  const int tid = threadIdx.x; const int l = tid&63, w = tid>>6;
  const int rbase = blockIdx.x*16;
  __shared__ u16 hlds[16][136];
  __shared__ int chs[16][16];
  __shared__ int cidx[16];
  for (int i = tid; i < 16*136; i += 512) ((u16*)hlds)[i] = 0;
  if (tid < 256) chs[tid>>4][tid&15] = chars[(size_t)(rbase + (tid>>4))*16 + (tid&15)];
  if (tid < 16){ int cl = char_len[rbase+tid]-1; cidx[tid] = cl<0?0:(cl>15?15:cl); }
  short8 bq[4][4];
  #pragma unroll
  for (int tt=0;tt<4;tt++)
    #pragma unroll
    for(int ks=0;ks<4;ks++)
      bq[tt][ks] = *((const short8*)whcf + (((w*4+tt)*4+ks)*64 + l));
  float c[4] = {0.f,0.f,0.f,0.f};
  const int u = w*16 + (l&15);
  __syncthreads();
  for (int s=0;s<16;s++){
    short8 a[4];
    #pragma unroll
    for (int ks=0;ks<4;ks++)
      a[ks] = *(const short8*)&hlds[l&15][ks*32 + ((l>>4)&3)*8];
    f32x4 acc[4];
    f32x4 zf4 = {0.f,0.f,0.f,0.f};
    #pragma unroll
    for (int tt=0;tt<4;tt++) acc[tt]=zf4;
    #pragma unroll
    for (int tt=0;tt<4;tt++)
      #pragma unroll
      for (int ks=0;ks<4;ks++)
        acc[tt] = __builtin_amdgcn_mfma_f32_16x16x32_bf16(a[ks], bq[tt][ks], acc[tt],0,0,0);
    float hv[4];
    #pragma unroll
    for (int q=0;q<4;q++){
      int r = ((l>>4)&3)*4 + q;
      int ch = chs[r][s];
      const float* tb = cgate + (size_t)ch*512 + u;
      float zi = tb[0]   + acc[0][q];
      float zf = tb[128] + acc[1][q];
      float zg = tb[256] + acc[2][q];
      float zo = tb[384] + acc[3][q];
      float cn = sigf(zf)*c[q] + sigf(zi)*tanhfast(zg);
      c[q] = cn;
      hv[q] = sigf(zo)*tanhfast(cn);
    }
    __syncthreads();
    #pragma unroll
    for (int q=0;q<4;q++){
      int r = ((l>>4)&3)*4 + q;
      u16 hb = f2bf(hv[q]);
      hlds[r][u] = hb;
      if (s == cidx[r]) xpad[(size_t)(rbase + r)*512 + 364 + u] = hb;
    }
    __syncthreads();
  }
}

// ---------------- main LSTM (fwd/bwd), one WG per direction ----------------
// 2 blocks x 512 thr (8 waves). fp8 register-resident Wh (x8), h fp8 via v_cvt_pk_fp8.
// X gate-packed [t][r][u][gate] bf16; hidden stores packed via v_cvt_pk_bf16_f32.
__global__ __launch_bounds__(512,2) void main_lstm(
  const u64* __restrict__ whq, const u16* __restrict__ xmain,
  const int* __restrict__ seq_len, u16* __restrict__ hidden){
  const int dir = blockIdx.x;
  const int tid = threadIdx.x; const int l = tid&63, w = tid>>6;
  const int l16 = l&15, q4 = (l>>4)&3;
  __shared__ unsigned char hlds[2][16][272];
  for (int i=tid; i<2*16*272; i+=512) ((unsigned char*)hlds)[i]=0;
  int sl[4];
  #pragma unroll
  for (int q=0;q<4;q++) sl[q] = seq_len[q4*4+q];
  u64 bq[8][8];
  #pragma unroll
  for (int tt=0;tt<8;tt++)
    #pragma unroll
    for(int ks=0;ks<8;ks++)
      bq[tt][ks] = whq[ (((size_t)(dir*8+w)*8+tt)*8+ks)*64 + l ];
  float c[8];
  #pragma unroll
  for (int i=0;i<8;i++) c[i]=0.f;
  const int u0 = w*32 + 2*l16;
  // thread-constant offsets (u16 units)
  int xoff[4], hoff[4];
  #pragma unroll
  for (int q=0;q<4;q++){
    int r = q4*4+q;
    xoff[q] = r*1024 + u0*4;            // [r][u][gate]
    hoff[q] = r*262144 + dir*256 + u0;  // [b][t][512]
  }
  const u16* xptr = xmain + (size_t)dir*8388608;
  u16* hptr = hidden + (size_t)(dir?511:0)*512;
  const int hstep = dir? -512 : 512;
  int t_src = dir? 511 : 0;
  const int ts_inc = dir? -1 : 1;
  int cur = 0;
  __syncthreads();
  #pragma unroll 1
  for (int t=0;t<512;t++){
    // X loads first (consumed last) — latency hides under MFMA
    uint4 xv[4];
    #pragma unroll
    for (int q=0;q<4;q++) xv[q] = *(const uint4*)(xptr + xoff[q]);
    u64 a[8];
    #pragma unroll
    for (int ks=0;ks<8;ks++)
      a[ks] = *(const u64*)&hlds[cur][l16][ks*32 + q4*8];
    f32x4 acc[8];
    f32x4 zf4 = {0.f,0.f,0.f,0.f};
    #pragma unroll
    for (int tt=0;tt<8;tt++) acc[tt]=zf4;
    #pragma unroll
    for (int tt=0;tt<8;tt++)
      #pragma unroll
      for (int ks=0;ks<8;ks++)
        acc[tt] = __builtin_amdgcn_mfma_f32_16x16x32_fp8_fp8((long)a[ks], (long)bq[tt][ks], acc[tt],0,0,0);
    #pragma unroll
    for (int q=0;q<4;q++){
      int r = q4*4+q;
      // unpack gates: xv[q] = {u0:(i,f),(g,o), u0+1:(i,f),(g,o)} bf16 pairs
      u32 w0 = xv[q].x, w1 = xv[q].y, w2 = xv[q].z, w3 = xv[q].w;
      float zi0 = __uint_as_float(w0<<16)          + 0.125f*acc[0][q];
      float zf0 = __uint_as_float(w0&0xFFFF0000u)  + 0.125f*acc[2][q];
      float zg0 = __uint_as_float(w1<<16)          + 0.125f*acc[4][q];
      float zo0 = __uint_as_float(w1&0xFFFF0000u)  + 0.125f*acc[6][q];
      float zi1 = __uint_as_float(w2<<16)          + 0.125f*acc[1][q];
      float zf1 = __uint_as_float(w2&0xFFFF0000u)  + 0.125f*acc[3][q];
      float zg1 = __uint_as_float(w3<<16)          + 0.125f*acc[5][q];
      float zo1 = __uint_as_float(w3&0xFFFF0000u)  + 0.125f*acc[7][q];
      float cn0 = sigf(zf0)*c[q*2]   + sigf(zi0)*tanhfast(zg0);
      float cn1 = sigf(zf1)*c[q*2+1] + sigf(zi1)*tanhfast(zg1);
      c[q*2]=cn0; c[q*2+1]=cn1;
      float h0 = sigf(zo0)*tanhfast(cn0);
      float h1 = sigf(zo1)*tanhfast(cn1);
      int pk = __builtin_amdgcn_cvt_pk_fp8_f32(h0, h1, 0, false);
      *(u16*)&hlds[cur^1][r][u0] = (u16)pk;
      u32 hb;
      asm("v_cvt_pk_bf16_f32 %0, %1, %2" : "=v"(hb) : "v"(h0), "v"(h1));
      hb = (t_src < sl[q]) ? hb : 0u;
      *(u32*)(hptr + hoff[q]) = hb;
    }
    __syncthreads();
    cur ^= 1;
    xptr += 16384;
    hptr += hstep;
    t_src += ts_inc;
  }
}

// ---------------- generic MFMA GEMM (A row-major bf16, B frag-packed) ----------------
__global__ __launch_bounds__(256) void gemm_frag(
    const u16* __restrict__ A, const u16* __restrict__ Bf,
    int N, int K, int mode,
    const float* __restrict__ bias0, const float* __restrict__ bias1,
    u16* __restrict__ out, const u16* __restrict__ hid){
  const int tid = threadIdx.x;
  const int l = tid & 63, w = tid >> 6;
  const int row0 = blockIdx.x*64 + w*16;
  const int col0 = blockIdx.y*128;
  const int Nt16 = N>>4;
  f32x4 acc[8];
  f32x4 zf4 = {0.f,0.f,0.f,0.f};
  #pragma unroll
  for (int i=0;i<8;i++) acc[i]=zf4;
  const int rl = row0 + (l&15);
  const int kb = ((l>>4)&3)*8;
  const int nK = K>>5;
  for (int ks=0; ks<nK; ++ks){
    int kc = ks*32 + kb;
    short8 a;
    if (mode==1){
      int b = rl>>9, t = rl&511;
      if (kc < 512){
        if (t==0){ short8 z8={0,0,0,0,0,0,0,0}; a=z8; }
        else a = *(const short8*)(hid + ((size_t)(b*512 + t-1)*512 + kc));
      } else {
        a = *(const short8*)(hid + ((size_t)(b*512 + t)*512 + (kc-512)));
      }
    } else {
      a = *(const short8*)(A + ((size_t)rl*K + kc));
    }
    const short8* bp = (const short8*)Bf + ((size_t)ks*Nt16 + (col0>>4))*64 + l;
    #pragma unroll
    for (int n=0;n<8;n++){
      short8 b8 = bp[n*64];
      acc[n] = __builtin_amdgcn_mfma_f32_16x16x32_bf16(a, b8, acc[n], 0,0,0);
    }
  }
  #pragma unroll
  for (int n=0;n<8;n++){
    int col = col0 + n*16 + (l&15);
    #pragma unroll
    for (int q=0;q<4;q++){
      int row = row0 + ((l>>4)&3)*4 + q;
      float v = acc[n][q];
      if (mode==0){
        int d = col>>10, c1 = col&1023;
        v += (d ? bias1 : bias0)[(c1&3)*256 + (c1>>2)];
        int b = row>>9, t = row&511;
        int t2 = d ? (511-t) : t;
        out[((size_t)(d*512 + t2)*16 + b)*1024 + c1] = f2bf(v);
      } else if (mode==1){
        v += (col<512)? bias0[col] : bias1[col-512];
        v = fmaxf(v, 0.f);
        out[(size_t)row*1024 + col] = f2bf(v);
      } else {
        out[(size_t)row*1024 + col] = f2bf(v);
      }
    }
  }
}

// ---------------- ll/lr ----------------
__global__ __launch_bounds__(256) void lin_kernel(const u16* __restrict__ flfr,
    const float* __restrict__ lw, const float* __restrict__ lb,
    const float* __restrict__ rw, const float* __restrict__ rb,
    float* __restrict__ llr){
  int row = blockIdx.x*4 + (threadIdx.x>>6);
  int l = threadIdx.x&63;
  const u16* fr = flfr + (size_t)row*1024;
  float pl=0.f, pr=0.f;
  #pragma unroll
  for (int j=0;j<8;j++){
    int ci = l*8+j;
    pl += bf2f(fr[ci]) * lw[ci];
    pr += bf2f(fr[512+ci]) * rw[ci];
  }
  #pragma unroll
  for (int off=32; off; off>>=1){ pl += __shfl_xor(pl, off, 64); pr += __shfl_xor(pr, off, 64); }
  if (l==0){ llr[row] = pl + lb[0]; llr[8192+row] = pr + rb[0]; }
}

// ---------------- banded bilinear + softmax ----------------
__global__ __launch_bounds__(256) void band_softmax(
  const u16* __restrict__ ulur, const u16* __restrict__ flfr,
  const float* __restrict__ llr, float* __restrict__ outp){
  int row = blockIdx.x*4 + (threadIdx.x>>6);
  int l = threadIdx.x&63;
  int b = row>>9, i = row&511;
  float ul[8], ur[8];
  const u16* up = ulur + (size_t)row*1024;
  #pragma unroll
  for (int j=0;j<8;j++){ ul[j]=bf2f(up[l*8+j]); ur[j]=bf2f(up[512+l*8+j]); }
  float sL = -1e30f, sR = -1e30f;
  for (int idx=0; idx<16; ++idx){
    int jL = i - idx;
    float p = 0.f;
    if (jL >= 0){
      const u16* f = flfr + (size_t)(b*512+jL)*1024;
      #pragma unroll
      for (int j=0;j<8;j++) p += ul[j]*bf2f(f[l*8+j]);
    }
    #pragma unroll
    for (int off=32; off; off>>=1) p += __shfl_xor(p, off, 64);
    if (l==idx && jL>=0) sL = p + llr[b*512+jL];
    int jR = i + idx;
    float pr_ = 0.f;
    if (jR < 512){
      const u16* f = flfr + (size_t)(b*512+jR)*1024;
      #pragma unroll
      for (int j=0;j<8;j++) pr_ += ur[j]*bf2f(f[512+l*8+j]);
    }
    #pragma unroll
    for (int off=32; off; off>>=1) pr_ += __shfl_xor(pr_, off, 64);
    if (l==idx && jR<512) sR = pr_ + llr[8192+b*512+jR];
  }
  float mL = sL, mR = sR;
  #pragma unroll
  for (int off=8; off; off>>=1){ mL = fmaxf(mL, __shfl_xor(mL, off, 16)); mR = fmaxf(mR, __shfl_xor(mR, off, 16)); }
  float eL = (sL>-1e29f)? __expf(sL-mL) : 0.f;
  float eR = (sR>-1e29f)? __expf(sR-mR) : 0.f;
  float suL = eL, suR = eR;
  #pragma unroll
  for (int off=8; off; off>>=1){ suL += __shfl_xor(suL, off, 16); suR += __shfl_xor(suR, off, 16); }
  float pL = eL/suL, pR = eR/suR;
  size_t obase = ((size_t)b*512 + i)*512;
  float vl[8], vr[8];
  #pragma unroll
  for (int j=0;j<8;j++){
    int ci = l*8+j;
    int ixl = i - ci;
    float v1 = __shfl(pL, ixl & 15, 64);
    vl[j] = (ixl>=0 && ixl<16) ? v1 : 0.f;
    int ixr = ci - i;
    float v2 = __shfl(pR, ixr & 15, 64);
    vr[j] = (ixr>=0 && ixr<16) ? v2 : 0.f;
  }
  float4* oL = (float4*)(outp + obase + l*8);
  oL[0] = make_float4(vl[0],vl[1],vl[2],vl[3]);
  oL[1] = make_float4(vl[4],vl[5],vl[6],vl[7]);
  float4* oR = (float4*)(outp + (size_t)16*512*512 + obase + l*8);
  oR[0] = make_float4(vr[0],vr[1],vr[2],vr[3]);
  oR[1] = make_float4(vr[4],vr[5],vr[6],vr[7]);
}

// ---------------- host launch ----------------
extern "C" void kernel_launch(void* const* d_in, const int* in_sizes, int n_in,
                              void* d_out, int out_size, void* d_ws, size_t ws_size,
                              hipStream_t stream) {
  const int* words    = (const int*)d_in[0];
  const int* poss     = (const int*)d_in[1];
  const int* seq_len  = (const int*)d_in[2];
  const int* chars    = (const int*)d_in[3];
  const int* char_len = (const int*)d_in[4];
  const float* word_emb = (const float*)d_in[6];
  const float* pos_emb  = (const float*)d_in[7];
  const float* char_emb = (const float*)d_in[8];
  const float* cWi = (const float*)d_in[9];
  const float* cWh = (const float*)d_in[10];
  const float* cb  = (const float*)d_in[11];
  const float* fWi = (const float*)d_in[12];
  const float* fWh = (const float*)d_in[13];
  const float* fb  = (const float*)d_in[14];
  const float* bWi = (const float*)d_in[15];
  const float* bWh = (const float*)d_in[16];
  const float* bb  = (const float*)d_in[17];
  const float* convL_k = (const float*)d_in[18];
  const float* convL_b = (const float*)d_in[19];
  const float* convR_k = (const float*)d_in[20];
  const float* convR_b = (const float*)d_in[21];
  const float* bilinL  = (const float*)d_in[22];
  const float* bilinR  = (const float*)d_in[23];
  const float* linL_w  = (const float*)d_in[24];
  const float* linL_b  = (const float*)d_in[25];
  const float* linR_w  = (const float*)d_in[26];
  const float* linR_b  = (const float*)d_in[27];

  char* ws = (char*)d_ws;
  constexpr size_t OFF_WHQ = 0;
  constexpr size_t OFF_WHC = OFF_WHQ + 524288;
  constexpr size_t OFF_WIF = OFF_WHC + 131072;
  constexpr size_t OFF_CVF = OFF_WIF + 2097152;
  constexpr size_t OFF_BLF = OFF_CVF + 2097152;
  constexpr size_t OFF_CGT = OFF_BLF + 1048576;
  constexpr size_t OFF_XPD = OFF_CGT + 262144;
  constexpr size_t OFF_XMN = OFF_XPD + 8388608;
  constexpr size_t OFF_HID = OFF_XMN + 33554432;
  constexpr size_t OFF_FLR = OFF_HID + 8388608;
  constexpr size_t OFF_ULR = OFF_FLR + 16777216;
  constexpr size_t OFF_LLR = OFF_ULR + 16777216;

  pack_whq<<<1024,64,0,stream>>>(fWh,bWh,(u64*)(ws+OFF_WHQ));
  pack_whc<<<128,64,0,stream>>>(cWh,(u16*)(ws+OFF_WHC));
  pack_bfrag<<<2048,64,0,stream>>>(fWi,bWi,(u16*)(ws+OFF_WIF),2048,512,0);
  pack_bfrag<<<2048,64,0,stream>>>(convL_k,convR_k,(u16*)(ws+OFF_CVF),1024,1024,1);
  pack_bfrag<<<1024,64,0,stream>>>(bilinL,bilinR,(u16*)(ws+OFF_BLF),1024,512,2);
  prep_cgate<<<128,256,0,stream>>>(char_emb,cWi,cb,(float*)(ws+OFF_CGT));
  embed_gather<<<8192,128,0,stream>>>(words,poss,word_emb,pos_emb,(u16*)(ws+OFF_XPD));
  char_lstm<<<512,512,0,stream>>>((const u16*)(ws+OFF_WHC),(const float*)(ws+OFF_CGT),
                                  chars,char_len,(u16*)(ws+OFF_XPD));
  gemm_frag<<<dim3(128,16),256,0,stream>>>((const u16*)(ws+OFF_XPD),(const u16*)(ws+OFF_WIF),
                                  2048,512,0,fb,bb,(u16*)(ws+OFF_XMN),nullptr);
  main_lstm<<<2,512,0,stream>>>((const u64*)(ws+OFF_WHQ),(const u16*)(ws+OFF_XMN),
                                  seq_len,(u16*)(ws+OFF_HID));
  gemm_frag<<<dim3(128,8),256,0,stream>>>(nullptr,(const u16*)(ws+OFF_CVF),
                                  1024,1024,1,convL_b,convR_b,(u16*)(ws+OFF_FLR),(const u16*)(ws+OFF_HID));
  gemm_frag<<<dim3(128,8),256,0,stream>>>((const u16*)(ws+OFF_HID),(const u16*)(ws+OFF_BLF),
                                  1024,512,2,convL_b,convR_b,(u16*)(ws+OFF_ULR),nullptr);
  lin_kernel<<<2048,256,0,stream>>>((const u16*)(ws+OFF_FLR),linL_w,linL_b,linR_w,linR_b,
                                  (float*)(ws+OFF_LLR));
  band_softmax<<<2048,256,0,stream>>>((const u16*)(ws+OFF_ULR),(const u16*)(ws+OFF_FLR),
                                  (const float*)(ws+OFF_LLR),(float*)d_out);
}

// Round 5
// 1635.137 us; speedup vs baseline: 1.7699x; 1.5038x over previous
//
#include <hip/hip_runtime.h>

typedef unsigned short u16;
typedef unsigned int   u32;
typedef unsigned long long u64;
typedef __attribute__((ext_vector_type(8))) short short8;
typedef __attribute__((ext_vector_type(4))) float f32x4;

#define DEV static __device__ __forceinline__

#define LOG2E 1.44269504f

DEV float bf2f(u16 u){ return __uint_as_float(((u32)u)<<16); }
DEV u16 f2bf(float f){ u32 u=__float_as_uint(f); return (u16)((u + 0x7FFFu + ((u>>16)&1u))>>16); }
DEV float sigf(float x){ return 1.f/(1.f+__expf(-x)); }
DEV float tanhfast(float x){ return 2.f*sigf(2.f*x)-1.f; }

// raw-rate transcendentals
DEV float ex2(float x){ float r; asm("v_exp_f32 %0, %1" : "=v"(r) : "v"(x)); return r; }
DEV float rcpf_(float x){ float r; asm("v_rcp_f32 %0, %1" : "=v"(r) : "v"(x)); return r; }
// zp = -1.4427*z  ->  sigmoid(z)
DEV float sig2(float zp){ return rcpf_(1.f + ex2(zp)); }
// gp = 2.8854*g  ->  tanh(g)
DEV float tanh2(float gp){ float e = ex2(gp); return (e-1.f)*rcpf_(e+1.f); }

// float -> OCP e4m3fn (host-prep only; hot path uses v_cvt_pk_fp8_f32)
DEV unsigned char f2e4m3(float x){
  u32 u = __float_as_uint(x);
  u32 s = (u>>31)<<7;
  u &= 0x7FFFFFFFu;
  if (u >= 0x43DC0000u) return (unsigned char)(s|0x7E);
  if (u <  0x3A800000u) return (unsigned char)s;
  u32 ur = u + 0x00080000u;
  int expn = (int)(ur>>23) - 127;
  u32 man = (ur>>20)&7u;
  if (expn < -6){
    float ax = __uint_as_float(u);
    int q = (int)rintf(ax*512.f);
    if (q>=8) return (unsigned char)(s|0x08);
    return (unsigned char)(s|(u32)q);
  }
  return (unsigned char)(s | ((u32)(expn+7)<<3) | man);
}

// ---------------- prep kernels ----------------

__global__ void prep_cgate(const float* __restrict__ emb, const float* __restrict__ cWi,
                           const float* __restrict__ cb, float* __restrict__ tab){
  int c = blockIdx.x;
  for (int g = threadIdx.x; g < 512; g += 256){
    float sacc = cb[g];
    for (int k=0;k<64;k++) sacc += emb[c*64+k]*cWi[k*512+g];
    tab[c*512+g]=sacc;
  }
}

// pack main-LSTM recurrent weights fp8 x8*sc[gate], frag-major: [dir][w8][tt8][ks8][lane64] u64
// tt = gate*2 + parity; tile cols: u = w*32 + 2*(l&15) + p ; src col = gate*256 + u
__global__ void pack_whq(const float* __restrict__ fWh, const float* __restrict__ bWh,
                         u64* __restrict__ whq){
  int blk = blockIdx.x;            // 1024
  int l = threadIdx.x;             // 64
  int ks = blk&7, tt=(blk>>3)&7, w=(blk>>6)&7, dir=blk>>9;
  const float* W = dir? bWh : fWh;
  int gate = tt>>1;
  float sc = (gate==2) ? (2.f*LOG2E) : (-LOG2E);
  int col = gate*256 + w*32 + 2*(l&15) + (tt&1);
  u64 v=0;
  for (int j=0;j<8;j++){
    int k = ks*32 + ((l>>4)&3)*8 + j;
    unsigned char q = f2e4m3(W[(size_t)k*1024+col]*8.f*sc);
    v |= ((u64)q)<<(8*j);
  }
  whq[(size_t)blk*64 + l] = v;
}

// pack char-LSTM recurrent weights bf16, frag-major: [w8][tt4][ks4][lane64] 8xbf16
__global__ void pack_whc(const float* __restrict__ cWh, u16* __restrict__ whc){
  int blk=blockIdx.x;              // 128
  int l=threadIdx.x;
  int ks=blk&3, tt=(blk>>2)&3, w=blk>>4;
  int col = 128*tt + 16*w + (l&15);
  u16 vals[8];
  for (int j=0;j<8;j++){
    int k = ks*32 + ((l>>4)&3)*8 + j;
    vals[j] = f2bf(cWh[(size_t)k*512+col]);
  }
  *((uint4*)whc + (size_t)blk*64 + l) = *(uint4*)vals;
}

// generic bf16 B-fragment pack: dst[(ks*(N/16)+n)*64+l] = 8 bf16 (k-consecutive)
// mode 0: Wi concat (fWi|bWi), K=512 (pad from 492), cols gate-interleaved: c1=u*4+gate
// mode 1: conv taps; mode 2: bilin concat
__global__ void pack_bfrag(const float* __restrict__ S0, const float* __restrict__ S1,
                           u16* __restrict__ dst, int N, int K, int mode){
  int blk = blockIdx.x; int l = threadIdx.x;
  int Nt = N>>4;
  int ks = blk / Nt, n = blk % Nt;
  int col = n*16 + (l&15);
  u16 vals[8];
  for (int j=0;j<8;j++){
    int k = ks*32 + ((l>>4)&3)*8 + j;
    float v;
    if (mode==0){
      int d = col>>10, c1 = col&1023;
      int srccol = (c1&3)*256 + (c1>>2);
      v = (k<492) ? (d ? S1[(size_t)k*1024+srccol] : S0[(size_t)k*1024+srccol]) : 0.f;
    } else if (mode==1){
      int tap=k>>9, kk=k&511;
      v = (col<512) ? S0[((size_t)tap*512+kk)*512+col] : S1[((size_t)tap*512+kk)*512+col-512];
    } else {
      v = (col<512) ? S0[(size_t)k*512+col] : S1[(size_t)k*512+col-512];
    }
    vals[j]=f2bf(v);
  }
  *((uint4*)dst + (size_t)blk*64 + l) = *(uint4*)vals;
}

// word/pos embedding gather into xpad[8192][512] bf16
__global__ void embed_gather(const int* __restrict__ words, const int* __restrict__ poss,
                             const float* __restrict__ wemb, const float* __restrict__ pemb,
                             u16* __restrict__ xpad){
  int row = blockIdx.x; int tid = threadIdx.x;   // 128 threads
  int wd = words[row], ps = poss[row];
  const float* wsrc = wemb + (size_t)wd*300;
  u16* xr = xpad + (size_t)row*512;
  for (int i=tid;i<300;i+=128) xr[i] = f2bf(wsrc[i]);
  if (tid<64) xr[300+tid] = f2bf(pemb[(size_t)ps*64+tid]);
  if (tid>=108) xr[492 + (tid-108)] = 0;
}

// ---------------- char LSTM ----------------
__global__ __launch_bounds__(512) void char_lstm(
  const u16* __restrict__ whcf, const float* __restrict__ cgate,
  const int* __restrict__ chars, const int* __restrict__ char_len,
  u16* __restrict__ xpad){
  const int tid = threadIdx.x; const int l = tid&63, w = tid>>6;
  const int rbase = blockIdx.x*16;
  __shared__ u16 hlds[16][136];
  __shared__ int chs[16][16];
  __shared__ int cidx[16];
  for (int i = tid; i < 16*136; i += 512) ((u16*)hlds)[i] = 0;
  if (tid < 256) chs[tid>>4][tid&15] = chars[(size_t)(rbase + (tid>>4))*16 + (tid&15)];
  if (tid < 16){ int cl = char_len[rbase+tid]-1; cidx[tid] = cl<0?0:(cl>15?15:cl); }
  short8 bq[4][4];
  #pragma unroll
  for (int tt=0;tt<4;tt++)
    #pragma unroll
    for(int ks=0;ks<4;ks++)
      bq[tt][ks] = *((const short8*)whcf + (((w*4+tt)*4+ks)*64 + l));
  float c[4] = {0.f,0.f,0.f,0.f};
  const int u = w*16 + (l&15);
  __syncthreads();
  for (int s=0;s<16;s++){
    short8 a[4];
    #pragma unroll
    for (int ks=0;ks<4;ks++)
      a[ks] = *(const short8*)&hlds[l&15][ks*32 + ((l>>4)&3)*8];
    f32x4 acc[4];
    f32x4 zf4 = {0.f,0.f,0.f,0.f};
    #pragma unroll
    for (int tt=0;tt<4;tt++) acc[tt]=zf4;
    #pragma unroll
    for (int tt=0;tt<4;tt++)
      #pragma unroll
      for (int ks=0;ks<4;ks++)
        acc[tt] = __builtin_amdgcn_mfma_f32_16x16x32_bf16(a[ks], bq[tt][ks], acc[tt],0,0,0);
    float hv[4];
    #pragma unroll
    for (int q=0;q<4;q++){
      int r = ((l>>4)&3)*4 + q;
      int ch = chs[r][s];
      const float* tb = cgate + (size_t)ch*512 + u;
      float zi = tb[0]   + acc[0][q];
      float zf = tb[128] + acc[1][q];
      float zg = tb[256] + acc[2][q];
      float zo = tb[384] + acc[3][q];
      float cn = sigf(zf)*c[q] + sigf(zi)*tanhfast(zg);
      c[q] = cn;
      hv[q] = sigf(zo)*tanhfast(cn);
    }
    __syncthreads();
    #pragma unroll
    for (int q=0;q<4;q++){
      int r = ((l>>4)&3)*4 + q;
      u16 hb = f2bf(hv[q]);
      hlds[r][u] = hb;
      if (s == cidx[r]) xpad[(size_t)(rbase + r)*512 + 364 + u] = hb;
    }
    __syncthreads();
  }
}

// ---------------- main LSTM (fwd/bwd), one WG per direction ----------------
// 2 blocks x 512 thr (8 waves). fp8 register-resident Wh (asm-pinned), pre-scaled by
// +-log2e so gates are raw v_exp_f32/v_rcp_f32. Even tiles -> h0 gates -> odd tiles
// -> h1 gates, so the scheduler interleaves MFMA with gate VALU.
__global__ __launch_bounds__(512,2) void main_lstm(
  const u64* __restrict__ whq, const u16* __restrict__ xmain,
  const int* __restrict__ seq_len, u16* __restrict__ hidden){
  const int dir = blockIdx.x;
  const int tid = threadIdx.x; const int l = tid&63, w = tid>>6;
  const int l16 = l&15, q4 = (l>>4)&3;
  __shared__ unsigned char hlds[2][16][272];
  for (int i=tid; i<2*16*272; i+=512) ((unsigned char*)hlds)[i]=0;
  int sl[4];
  #pragma unroll
  for (int q=0;q<4;q++) sl[q] = seq_len[q4*4+q];
  u64 bq[8][8];
  #pragma unroll
  for (int tt=0;tt<8;tt++)
    #pragma unroll
    for(int ks=0;ks<8;ks++){
      bq[tt][ks] = whq[ (((size_t)(dir*8+w)*8+tt)*8+ks)*64 + l ];
      asm volatile("" : "+v"(bq[tt][ks]));   // pin: no remat/sink into the loop
    }
  float c[8];
  #pragma unroll
  for (int i=0;i<8;i++) c[i]=0.f;
  const int u0 = w*32 + 2*l16;
  int xoff[4], hoff[4];
  #pragma unroll
  for (int q=0;q<4;q++){
    int r = q4*4+q;
    xoff[q] = r*1024 + u0*4;            // [r][u][gate]
    hoff[q] = r*262144 + dir*256 + u0;  // [b][t][512]
  }
  const u16* xptr = xmain + (size_t)dir*8388608;
  u16* hptr = hidden + (size_t)(dir?511:0)*512;
  const int hstep = dir? -512 : 512;
  int t_src = dir? 511 : 0;
  const int ts_inc = dir? -1 : 1;
  int cur = 0;
  __syncthreads();
  #pragma unroll 1
  for (int t=0;t<512;t++){
    uint4 xv[4];
    #pragma unroll
    for (int q=0;q<4;q++) xv[q] = *(const uint4*)(xptr + xoff[q]);
    u64 a[8];
    #pragma unroll
    for (int ks=0;ks<8;ks++)
      a[ks] = *(const u64*)&hlds[cur][l16][ks*32 + q4*8];
    f32x4 acc[8];
    f32x4 zf4 = {0.f,0.f,0.f,0.f};
    #pragma unroll
    for (int tt=0;tt<8;tt++) acc[tt]=zf4;
    // even tiles: unit u0
    #pragma unroll
    for (int g=0;g<4;g++)
      #pragma unroll
      for (int ks=0;ks<8;ks++)
        acc[g*2] = __builtin_amdgcn_mfma_f32_16x16x32_fp8_fp8((long)a[ks], (long)bq[g*2][ks], acc[g*2],0,0,0);
    // gates for u0 (overlaps odd-tile MFMAs in the scheduler)
    float hv0[4];
    #pragma unroll
    for (int q=0;q<4;q++){
      u32 w0 = xv[q].x, w1 = xv[q].y;
      float zi = __uint_as_float(w0<<16)          + 0.125f*acc[0][q];
      float zf = __uint_as_float(w0&0xFFFF0000u)  + 0.125f*acc[2][q];
      float zg = __uint_as_float(w1<<16)          + 0.125f*acc[4][q];
      float zo = __uint_as_float(w1&0xFFFF0000u)  + 0.125f*acc[6][q];
      float si = sig2(zi), sf = sig2(zf), so = sig2(zo), tg = tanh2(zg);
      float cn = sf*c[q*2] + si*tg;
      c[q*2] = cn;
      hv0[q] = so * tanh2(cn*(2.f*LOG2E));
    }
    // odd tiles: unit u0+1
    #pragma unroll
    for (int g=0;g<4;g++)
      #pragma unroll
      for (int ks=0;ks<8;ks++)
        acc[g*2+1] = __builtin_amdgcn_mfma_f32_16x16x32_fp8_fp8((long)a[ks], (long)bq[g*2+1][ks], acc[g*2+1],0,0,0);
    float hv1[4];
    #pragma unroll
    for (int q=0;q<4;q++){
      u32 w2 = xv[q].z, w3 = xv[q].w;
      float zi = __uint_as_float(w2<<16)          + 0.125f*acc[1][q];
      float zf = __uint_as_float(w2&0xFFFF0000u)  + 0.125f*acc[3][q];
      float zg = __uint_as_float(w3<<16)          + 0.125f*acc[5][q];
      float zo = __uint_as_float(w3&0xFFFF0000u)  + 0.125f*acc[7][q];
      float si = sig2(zi), sf = sig2(zf), so = sig2(zo), tg = tanh2(zg);
      float cn = sf*c[q*2+1] + si*tg;
      c[q*2+1] = cn;
      hv1[q] = so * tanh2(cn*(2.f*LOG2E));
    }
    #pragma unroll
    for (int q=0;q<4;q++){
      int r = q4*4+q;
      int pk = __builtin_amdgcn_cvt_pk_fp8_f32(hv0[q], hv1[q], 0, false);
      *(u16*)&hlds[cur^1][r][u0] = (u16)pk;
      u32 hb;
      asm("v_cvt_pk_bf16_f32 %0, %1, %2" : "=v"(hb) : "v"(hv0[q]), "v"(hv1[q]));
      hb = (t_src < sl[q]) ? hb : 0u;
      *(u32*)(hptr + hoff[q]) = hb;
    }
    __syncthreads();
    cur ^= 1;
    xptr += 16384;
    hptr += hstep;
    t_src += ts_inc;
  }
}

// ---------------- generic MFMA GEMM (A row-major bf16, B frag-packed) ----------------
__global__ __launch_bounds__(256) void gemm_frag(
    const u16* __restrict__ A, const u16* __restrict__ Bf,
    int N, int K, int mode,
    const float* __restrict__ bias0, const float* __restrict__ bias1,
    u16* __restrict__ out, const u16* __restrict__ hid){
  const int tid = threadIdx.x;
  const int l = tid & 63, w = tid >> 6;
  const int row0 = blockIdx.x*64 + w*16;
  const int col0 = blockIdx.y*128;
  const int Nt16 = N>>4;
  f32x4 acc[8];
  f32x4 zf4 = {0.f,0.f,0.f,0.f};
  #pragma unroll
  for (int i=0;i<8;i++) acc[i]=zf4;
  const int rl = row0 + (l&15);
  const int kb = ((l>>4)&3)*8;
  const int nK = K>>5;
  for (int ks=0; ks<nK; ++ks){
    int kc = ks*32 + kb;
    short8 a;
    if (mode==1){
      int b = rl>>9, t = rl&511;
      if (kc < 512){
        if (t==0){ short8 z8={0,0,0,0,0,0,0,0}; a=z8; }
        else a = *(const short8*)(hid + ((size_t)(b*512 + t-1)*512 + kc));
      } else {
        a = *(const short8*)(hid + ((size_t)(b*512 + t)*512 + (kc-512)));
      }
    } else {
      a = *(const short8*)(A + ((size_t)rl*K + kc));
    }
    const short8* bp = (const short8*)Bf + ((size_t)ks*Nt16 + (col0>>4))*64 + l;
    #pragma unroll
    for (int n=0;n<8;n++){
      short8 b8 = bp[n*64];
      acc[n] = __builtin_amdgcn_mfma_f32_16x16x32_bf16(a, b8, acc[n], 0,0,0);
    }
  }
  // mode 0: gate scale (exp2-domain pre-scale); c1&3 == l&3 (thread-constant)
  float scg = ((l&3)==2) ? (2.f*LOG2E) : (-LOG2E);
  #pragma unroll
  for (int n=0;n<8;n++){
    int col = col0 + n*16 + (l&15);
    #pragma unroll
    for (int q=0;q<4;q++){
      int row = row0 + ((l>>4)&3)*4 + q;
      float v = acc[n][q];
      if (mode==0){
        int d = col>>10, c1 = col&1023;
        v = (v + (d ? bias1 : bias0)[(c1&3)*256 + (c1>>2)]) * scg;
        int b = row>>9, t = row&511;
        int t2 = d ? (511-t) : t;
        out[((size_t)(d*512 + t2)*16 + b)*1024 + c1] = f2bf(v);
      } else if (mode==1){
        v += (col<512)? bias0[col] : bias1[col-512];
        v = fmaxf(v, 0.f);
        out[(size_t)row*1024 + col] = f2bf(v);
      } else {
        out[(size_t)row*1024 + col] = f2bf(v);
      }
    }
  }
}

// ---------------- ll/lr ----------------
__global__ __launch_bounds__(256) void lin_kernel(const u16* __restrict__ flfr,
    const float* __restrict__ lw, const float* __restrict__ lb,
    const float* __restrict__ rw, const float* __restrict__ rb,
    float* __restrict__ llr){
  int row = blockIdx.x*4 + (threadIdx.x>>6);
  int l = threadIdx.x&63;
  const u16* fr = flfr + (size_t)row*1024;
  float pl=0.f, pr=0.f;
  #pragma unroll
  for (int j=0;j<8;j++){
    int ci = l*8+j;
    pl += bf2f(fr[ci]) * lw[ci];
    pr += bf2f(fr[512+ci]) * rw[ci];
  }
  #pragma unroll
  for (int off=32; off; off>>=1){ pl += __shfl_xor(pl, off, 64); pr += __shfl_xor(pr, off, 64); }
  if (l==0){ llr[row] = pl + lb[0]; llr[8192+row] = pr + rb[0]; }
}

// ---------------- banded bilinear + softmax ----------------
__global__ __launch_bounds__(256) void band_softmax(
  const u16* __restrict__ ulur, const u16* __restrict__ flfr,
  const float* __restrict__ llr, float* __restrict__ outp){
  int row = blockIdx.x*4 + (threadIdx.x>>6);
  int l = threadIdx.x&63;
  int b = row>>9, i = row&511;
  float ul[8], ur[8];
  const u16* up = ulur + (size_t)row*1024;
  #pragma unroll
  for (int j=0;j<8;j++){ ul[j]=bf2f(up[l*8+j]); ur[j]=bf2f(up[512+l*8+j]); }
  float sL = -1e30f, sR = -1e30f;
  for (int idx=0; idx<16; ++idx){
    int jL = i - idx;
    float p = 0.f;
    if (jL >= 0){
      const u16* f = flfr + (size_t)(b*512+jL)*1024;
      #pragma unroll
      for (int j=0;j<8;j++) p += ul[j]*bf2f(f[l*8+j]);
    }
    #pragma unroll
    for (int off=32; off; off>>=1) p += __shfl_xor(p, off, 64);
    if (l==idx && jL>=0) sL = p + llr[b*512+jL];
    int jR = i + idx;
    float pr_ = 0.f;
    if (jR < 512){
      const u16* f = flfr + (size_t)(b*512+jR)*1024;
      #pragma unroll
      for (int j=0;j<8;j++) pr_ += ur[j]*bf2f(f[512+l*8+j]);
    }
    #pragma unroll
    for (int off=32; off; off>>=1) pr_ += __shfl_xor(pr_, off, 64);
    if (l==idx && jR<512) sR = pr_ + llr[8192+b*512+jR];
  }
  float mL = sL, mR = sR;
  #pragma unroll
  for (int off=8; off; off>>=1){ mL = fmaxf(mL, __shfl_xor(mL, off, 16)); mR = fmaxf(mR, __shfl_xor(mR, off, 16)); }
  float eL = (sL>-1e29f)? __expf(sL-mL) : 0.f;
  float eR = (sR>-1e29f)? __expf(sR-mR) : 0.f;
  float suL = eL, suR = eR;
  #pragma unroll
  for (int off=8; off; off>>=1){ suL += __shfl_xor(suL, off, 16); suR += __shfl_xor(suR, off, 16); }
  float pL = eL/suL, pR = eR/suR;
  size_t obase = ((size_t)b*512 + i)*512;
  float vl[8], vr[8];
  #pragma unroll
  for (int j=0;j<8;j++){
    int ci = l*8+j;
    int ixl = i - ci;
    float v1 = __shfl(pL, ixl & 15, 64);
    vl[j] = (ixl>=0 && ixl<16) ? v1 : 0.f;
    int ixr = ci - i;
    float v2 = __shfl(pR, ixr & 15, 64);
    vr[j] = (ixr>=0 && ixr<16) ? v2 : 0.f;
  }
  float4* oL = (float4*)(outp + obase + l*8);
  oL[0] = make_float4(vl[0],vl[1],vl[2],vl[3]);
  oL[1] = make_float4(vl[4],vl[5],vl[6],vl[7]);
  float4* oR = (float4*)(outp + (size_t)16*512*512 + obase + l*8);
  oR[0] = make_float4(vr[0],vr[1],vr[2],vr[3]);
  oR[1] = make_float4(vr[4],vr[5],vr[6],vr[7]);
}

// ---------------- host launch ----------------
extern "C" void kernel_launch(void* const* d_in, const int* in_sizes, int n_in,
                              void* d_out, int out_size, void* d_ws, size_t ws_size,
                              hipStream_t stream) {
  const int* words    = (const int*)d_in[0];
  const int* poss     = (const int*)d_in[1];
  const int* seq_len  = (const int*)d_in[2];
  const int* chars    = (const int*)d_in[3];
  const int* char_len = (const int*)d_in[4];
  const float* word_emb = (const float*)d_in[6];
  const float* pos_emb  = (const float*)d_in[7];
  const float* char_emb = (const float*)d_in[8];
  const float* cWi = (const float*)d_in[9];
  const float* cWh = (const float*)d_in[10];
  const float* cb  = (const float*)d_in[11];
  const float* fWi = (const float*)d_in[12];
  const float* fWh = (const float*)d_in[13];
  const float* fb  = (const float*)d_in[14];
  const float* bWi = (const float*)d_in[15];
  const float* bWh = (const float*)d_in[16];
  const float* bb  = (const float*)d_in[17];
  const float* convL_k = (const float*)d_in[18];
  const float* convL_b = (const float*)d_in[19];
  const float* convR_k = (const float*)d_in[20];
  const float* convR_b = (const float*)d_in[21];
  const float* bilinL  = (const float*)d_in[22];
  const float* bilinR  = (const float*)d_in[23];
  const float* linL_w  = (const float*)d_in[24];
  const float* linL_b  = (const float*)d_in[25];
  const float* linR_w  = (const float*)d_in[26];
  const float* linR_b  = (const float*)d_in[27];

  char* ws = (char*)d_ws;
  constexpr size_t OFF_WHQ = 0;
  constexpr size_t OFF_WHC = OFF_WHQ + 524288;
  constexpr size_t OFF_WIF = OFF_WHC + 131072;
  constexpr size_t OFF_CVF = OFF_WIF + 2097152;
  constexpr size_t OFF_BLF = OFF_CVF + 2097152;
  constexpr size_t OFF_CGT = OFF_BLF + 1048576;
  constexpr size_t OFF_XPD = OFF_CGT + 262144;
  constexpr size_t OFF_XMN = OFF_XPD + 8388608;
  constexpr size_t OFF_HID = OFF_XMN + 33554432;
  constexpr size_t OFF_FLR = OFF_HID + 8388608;
  constexpr size_t OFF_ULR = OFF_FLR + 16777216;
  constexpr size_t OFF_LLR = OFF_ULR + 16777216;

  pack_whq<<<1024,64,0,stream>>>(fWh,bWh,(u64*)(ws+OFF_WHQ));
  pack_whc<<<128,64,0,stream>>>(cWh,(u16*)(ws+OFF_WHC));
  pack_bfrag<<<2048,64,0,stream>>>(fWi,bWi,(u16*)(ws+OFF_WIF),2048,512,0);
  pack_bfrag<<<2048,64,0,stream>>>(convL_k,convR_k,(u16*)(ws+OFF_CVF),1024,1024,1);
  pack_bfrag<<<1024,64,0,stream>>>(bilinL,bilinR,(u16*)(ws+OFF_BLF),1024,512,2);
  prep_cgate<<<128,256,0,stream>>>(char_emb,cWi,cb,(float*)(ws+OFF_CGT));
  embed_gather<<<8192,128,0,stream>>>(words,poss,word_emb,pos_emb,(u16*)(ws+OFF_XPD));
  char_lstm<<<512,512,0,stream>>>((const u16*)(ws+OFF_WHC),(const float*)(ws+OFF_CGT),
                                  chars,char_len,(u16*)(ws+OFF_XPD));
  gemm_frag<<<dim3(128,16),256,0,stream>>>((const u16*)(ws+OFF_XPD),(const u16*)(ws+OFF_WIF),
                                  2048,512,0,fb,bb,(u16*)(ws+OFF_XMN),nullptr);
  main_lstm<<<2,512,0,stream>>>((const u64*)(ws+OFF_WHQ),(const u16*)(ws+OFF_XMN),
                                  seq_len,(u16*)(ws+OFF_HID));
  gemm_frag<<<dim3(128,8),256,0,stream>>>(nullptr,(const u16*)(ws+OFF_CVF),
                                  1024,1024,1,convL_b,convR_b,(u16*)(ws+OFF_FLR),(const u16*)(ws+OFF_HID));
  gemm_frag<<<dim3(128,8),256,0,stream>>>((const u16*)(ws+OFF_HID),(const u16*)(ws+OFF_BLF),
                                  1024,512,2,convL_b,convR_b,(u16*)(ws+OFF_ULR),nullptr);
  lin_kernel<<<2048,256,0,stream>>>((const u16*)(ws+OFF_FLR),linL_w,linL_b,linR_w,linR_b,
                                  (float*)(ws+OFF_LLR));
  band_softmax<<<2048,256,0,stream>>>((const u16*)(ws+OFF_ULR),(const u16*)(ws+OFF_FLR),
                                  (const float*)(ws+OFF_LLR),(float*)d_out);
}

// Round 6
// 1351.331 us; speedup vs baseline: 2.1416x; 1.2100x over previous
//
#include <hip/hip_runtime.h>

typedef unsigned short u16;
typedef unsigned int   u32;
typedef unsigned long long u64;
typedef __attribute__((ext_vector_type(8))) short short8;
typedef __attribute__((ext_vector_type(4))) float f32x4;

#define DEV static __device__ __forceinline__

#define LOG2E 1.44269504f

DEV float bf2f(u16 u){ return __uint_as_float(((u32)u)<<16); }
DEV u16 f2bf(float f){ u32 u=__float_as_uint(f); return (u16)((u + 0x7FFFu + ((u>>16)&1u))>>16); }
DEV float sigf(float x){ return 1.f/(1.f+__expf(-x)); }
DEV float tanhfast(float x){ return 2.f*sigf(2.f*x)-1.f; }

// raw-rate transcendentals
DEV float ex2(float x){ float r; asm("v_exp_f32 %0, %1" : "=v"(r) : "v"(x)); return r; }
DEV float rcpf_(float x){ float r; asm("v_rcp_f32 %0, %1" : "=v"(r) : "v"(x)); return r; }
// zp = -1.4427*z  ->  sigmoid(z)
DEV float sig2(float zp){ return rcpf_(1.f + ex2(zp)); }
// gp = 2.8854*g  ->  tanh(g)
DEV float tanh2(float gp){ float e = ex2(gp); return (e-1.f)*rcpf_(e+1.f); }

// float -> OCP e4m3fn (host-prep only; hot path uses v_cvt_pk_fp8_f32)
DEV unsigned char f2e4m3(float x){
  u32 u = __float_as_uint(x);
  u32 s = (u>>31)<<7;
  u &= 0x7FFFFFFFu;
  if (u >= 0x43DC0000u) return (unsigned char)(s|0x7E);
  if (u <  0x3A800000u) return (unsigned char)s;
  u32 ur = u + 0x00080000u;
  int expn = (int)(ur>>23) - 127;
  u32 man = (ur>>20)&7u;
  if (expn < -6){
    float ax = __uint_as_float(u);
    int q = (int)rintf(ax*512.f);
    if (q>=8) return (unsigned char)(s|0x08);
    return (unsigned char)(s|(u32)q);
  }
  return (unsigned char)(s | ((u32)(expn+7)<<3) | man);
}

// ---------------- prep kernels ----------------

__global__ void prep_cgate(const float* __restrict__ emb, const float* __restrict__ cWi,
                           const float* __restrict__ cb, float* __restrict__ tab){
  int c = blockIdx.x;
  for (int g = threadIdx.x; g < 512; g += 256){
    float sacc = cb[g];
    for (int k=0;k<64;k++) sacc += emb[c*64+k]*cWi[k*512+g];
    tab[c*512+g]=sacc;
  }
}

// pack main-LSTM recurrent weights fp8 x8*sc[gate], frag-major: [dir][w8][tt8][ks8][lane64] u64
// tt = gate*2 + parity; tile cols: u = w*32 + 2*(l&15) + p ; src col = gate*256 + u
__global__ void pack_whq(const float* __restrict__ fWh, const float* __restrict__ bWh,
                         u64* __restrict__ whq){
  int blk = blockIdx.x;            // 1024
  int l = threadIdx.x;             // 64
  int ks = blk&7, tt=(blk>>3)&7, w=(blk>>6)&7, dir=blk>>9;
  const float* W = dir? bWh : fWh;
  int gate = tt>>1;
  float sc = (gate==2) ? (2.f*LOG2E) : (-LOG2E);
  int col = gate*256 + w*32 + 2*(l&15) + (tt&1);
  u64 v=0;
  for (int j=0;j<8;j++){
    int k = ks*32 + ((l>>4)&3)*8 + j;
    unsigned char q = f2e4m3(W[(size_t)k*1024+col]*8.f*sc);
    v |= ((u64)q)<<(8*j);
  }
  whq[(size_t)blk*64 + l] = v;
}

// pack char-LSTM recurrent weights bf16, frag-major: [w8][tt4][ks4][lane64] 8xbf16
__global__ void pack_whc(const float* __restrict__ cWh, u16* __restrict__ whc){
  int blk=blockIdx.x;              // 128
  int l=threadIdx.x;
  int ks=blk&3, tt=(blk>>2)&3, w=blk>>4;
  int col = 128*tt + 16*w + (l&15);
  u16 vals[8];
  for (int j=0;j<8;j++){
    int k = ks*32 + ((l>>4)&3)*8 + j;
    vals[j] = f2bf(cWh[(size_t)k*512+col]);
  }
  *((uint4*)whc + (size_t)blk*64 + l) = *(uint4*)vals;
}

// generic bf16 B-fragment pack: dst[(ks*(N/16)+n)*64+l] = 8 bf16 (k-consecutive)
// mode 0: Wi concat (fWi|bWi), K=512 (pad from 492), cols gate-interleaved: c1=u*4+gate
// mode 1: conv taps; mode 2: bilin concat
__global__ void pack_bfrag(const float* __restrict__ S0, const float* __restrict__ S1,
                           u16* __restrict__ dst, int N, int K, int mode){
  int blk = blockIdx.x; int l = threadIdx.x;
  int Nt = N>>4;
  int ks = blk / Nt, n = blk % Nt;
  int col = n*16 + (l&15);
  u16 vals[8];
  for (int j=0;j<8;j++){
    int k = ks*32 + ((l>>4)&3)*8 + j;
    float v;
    if (mode==0){
      int d = col>>10, c1 = col&1023;
      int srccol = (c1&3)*256 + (c1>>2);
      v = (k<492) ? (d ? S1[(size_t)k*1024+srccol] : S0[(size_t)k*1024+srccol]) : 0.f;
    } else if (mode==1){
      int tap=k>>9, kk=k&511;
      v = (col<512) ? S0[((size_t)tap*512+kk)*512+col] : S1[((size_t)tap*512+kk)*512+col-512];
    } else {
      v = (col<512) ? S0[(size_t)k*512+col] : S1[(size_t)k*512+col-512];
    }
    vals[j]=f2bf(v);
  }
  *((uint4*)dst + (size_t)blk*64 + l) = *(uint4*)vals;
}

// word/pos embedding gather into xpad[8192][512] bf16
__global__ void embed_gather(const int* __restrict__ words, const int* __restrict__ poss,
                             const float* __restrict__ wemb, const float* __restrict__ pemb,
                             u16* __restrict__ xpad){
  int row = blockIdx.x; int tid = threadIdx.x;   // 128 threads
  int wd = words[row], ps = poss[row];
  const float* wsrc = wemb + (size_t)wd*300;
  u16* xr = xpad + (size_t)row*512;
  for (int i=tid;i<300;i+=128) xr[i] = f2bf(wsrc[i]);
  if (tid<64) xr[300+tid] = f2bf(pemb[(size_t)ps*64+tid]);
  if (tid>=108) xr[492 + (tid-108)] = 0;
}

// ---------------- char LSTM ----------------
__global__ __launch_bounds__(512) void char_lstm(
  const u16* __restrict__ whcf, const float* __restrict__ cgate,
  const int* __restrict__ chars, const int* __restrict__ char_len,
  u16* __restrict__ xpad){
  const int tid = threadIdx.x; const int l = tid&63, w = tid>>6;
  const int rbase = blockIdx.x*16;
  __shared__ u16 hlds[16][136];
  __shared__ int chs[16][16];
  __shared__ int cidx[16];
  for (int i = tid; i < 16*136; i += 512) ((u16*)hlds)[i] = 0;
  if (tid < 256) chs[tid>>4][tid&15] = chars[(size_t)(rbase + (tid>>4))*16 + (tid&15)];
  if (tid < 16){ int cl = char_len[rbase+tid]-1; cidx[tid] = cl<0?0:(cl>15?15:cl); }
  short8 bq[4][4];
  #pragma unroll
  for (int tt=0;tt<4;tt++)
    #pragma unroll
    for(int ks=0;ks<4;ks++)
      bq[tt][ks] = *((const short8*)whcf + (((w*4+tt)*4+ks)*64 + l));
  float c[4] = {0.f,0.f,0.f,0.f};
  const int u = w*16 + (l&15);
  __syncthreads();
  for (int s=0;s<16;s++){
    short8 a[4];
    #pragma unroll
    for (int ks=0;ks<4;ks++)
      a[ks] = *(const short8*)&hlds[l&15][ks*32 + ((l>>4)&3)*8];
    f32x4 acc[4];
    f32x4 zf4 = {0.f,0.f,0.f,0.f};
    #pragma unroll
    for (int tt=0;tt<4;tt++) acc[tt]=zf4;
    #pragma unroll
    for (int tt=0;tt<4;tt++)
      #pragma unroll
      for (int ks=0;ks<4;ks++)
        acc[tt] = __builtin_amdgcn_mfma_f32_16x16x32_bf16(a[ks], bq[tt][ks], acc[tt],0,0,0);
    float hv[4];
    #pragma unroll
    for (int q=0;q<4;q++){
      int r = ((l>>4)&3)*4 + q;
      int ch = chs[r][s];
      const float* tb = cgate + (size_t)ch*512 + u;
      float zi = tb[0]   + acc[0][q];
      float zf = tb[128] + acc[1][q];
      float zg = tb[256] + acc[2][q];
      float zo = tb[384] + acc[3][q];
      float cn = sigf(zf)*c[q] + sigf(zi)*tanhfast(zg);
      c[q] = cn;
      hv[q] = sigf(zo)*tanhfast(cn);
    }
    __syncthreads();
    #pragma unroll
    for (int q=0;q<4;q++){
      int r = ((l>>4)&3)*4 + q;
      u16 hb = f2bf(hv[q]);
      hlds[r][u] = hb;
      if (s == cidx[r]) xpad[(size_t)(rbase + r)*512 + 364 + u] = hb;
    }
    __syncthreads();
  }
}

// ---------------- main LSTM (fwd/bwd), 4 WGs per direction (batch-split) ----------------
// grid=8 x 512 thr. WG = (dir, 4 batch rows). fp8 register-resident Wh (asm-pinned).
// M=4 real rows (A rows 4-15 stay zero). After MFMA, acc (lanes 0-15 only) is
// redistributed through per-wave LDS so all 64 lanes share the gate VALU (2 h/thread).
__global__ __launch_bounds__(512,2) void main_lstm(
  const u64* __restrict__ whq, const u16* __restrict__ xmain,
  const int* __restrict__ seq_len, u16* __restrict__ hidden){
  const int wg = blockIdx.x;
  const int dir = wg>>2, rb4 = (wg&3)*4;
  const int tid = threadIdx.x; const int l = tid&63, w = tid>>6;
  const int l16 = l&15, q4 = (l>>4)&3;
  const int r = l&3, uu0 = (l>>2)*2;
  __shared__ unsigned char hlds[2][16][272];
  __shared__ float zlds[8][128][4];     // per-wave private region [w]
  for (int i=tid; i<2*16*272; i+=512) ((unsigned char*)hlds)[i]=0;
  const int slr = seq_len[rb4 + r];
  u64 bq[8][8];
  #pragma unroll
  for (int tt=0;tt<8;tt++)
    #pragma unroll
    for(int ks=0;ks<8;ks++){
      bq[tt][ks] = whq[ (((size_t)(dir*8+w)*8+tt)*8+ks)*64 + l ];
      asm volatile("" : "+v"(bq[tt][ks]));   // pin: no remat/sink into the loop
    }
  float c0 = 0.f, c1 = 0.f;
  const int xoff = (rb4 + r)*1024 + (w*32 + uu0)*4;            // [t][r][u][gate]
  const int hoff = (rb4 + r)*262144 + dir*256 + (w*32 + uu0);  // [b][t][512]
  const u16* xptr = xmain + (size_t)dir*8388608;
  u16* hptr = hidden + (size_t)(dir?511:0)*512;
  const int hstep = dir? -512 : 512;
  int t_src = dir? 511 : 0;
  const int ts_inc = dir? -1 : 1;
  int cur = 0;
  __syncthreads();
  #pragma unroll 1
  for (int t=0;t<512;t++){
    // X load first (consumed last) — latency hides under MFMA
    uint4 xv = *(const uint4*)(xptr + xoff);
    u64 a[8];
    #pragma unroll
    for (int ks=0;ks<8;ks++)
      a[ks] = *(const u64*)&hlds[cur][l16][ks*32 + q4*8];
    f32x4 acc[8];
    f32x4 zf4 = {0.f,0.f,0.f,0.f};
    #pragma unroll
    for (int tt=0;tt<8;tt++) acc[tt]=zf4;
    #pragma unroll
    for (int tt=0;tt<8;tt++)
      #pragma unroll
      for (int ks=0;ks<8;ks++)
        acc[tt] = __builtin_amdgcn_mfma_f32_16x16x32_fp8_fp8((long)a[ks], (long)bq[tt][ks], acc[tt],0,0,0);
    // redistribute: real acc rows (0-3) live in lanes 0-15; push to per-wave LDS
    if (l < 16){
      #pragma unroll
      for (int tt=0;tt<8;tt++)
        *(f32x4*)&zlds[w][(tt>>1)*32 + 2*l + (tt&1)][0] = acc[tt];
    }
    // wave-local write->read (same wave only): compiler inserts lgkmcnt wait
    float z0 = zlds[w][uu0][r],      z1 = zlds[w][uu0+1][r];
    float z2 = zlds[w][32+uu0][r],   z3 = zlds[w][32+uu0+1][r];
    float z4 = zlds[w][64+uu0][r],   z5 = zlds[w][64+uu0+1][r];
    float z6 = zlds[w][96+uu0][r],   z7 = zlds[w][96+uu0+1][r];
    // gates: 2 h-values per thread
    float zi0 = __uint_as_float(xv.x<<16)          + 0.125f*z0;
    float zf0 = __uint_as_float(xv.x&0xFFFF0000u)  + 0.125f*z2;
    float zg0 = __uint_as_float(xv.y<<16)          + 0.125f*z4;
    float zo0 = __uint_as_float(xv.y&0xFFFF0000u)  + 0.125f*z6;
    float zi1 = __uint_as_float(xv.z<<16)          + 0.125f*z1;
    float zf1 = __uint_as_float(xv.z&0xFFFF0000u)  + 0.125f*z3;
    float zg1 = __uint_as_float(xv.w<<16)          + 0.125f*z5;
    float zo1 = __uint_as_float(xv.w&0xFFFF0000u)  + 0.125f*z7;
    float si0 = sig2(zi0), sf0 = sig2(zf0), so0 = sig2(zo0), tg0 = tanh2(zg0);
    float cn0 = sf0*c0 + si0*tg0; c0 = cn0;
    float h0 = so0 * tanh2(cn0*(2.f*LOG2E));
    float si1 = sig2(zi1), sf1 = sig2(zf1), so1 = sig2(zo1), tg1 = tanh2(zg1);
    float cn1 = sf1*c1 + si1*tg1; c1 = cn1;
    float h1 = so1 * tanh2(cn1*(2.f*LOG2E));
    int pk = __builtin_amdgcn_cvt_pk_fp8_f32(h0, h1, 0, false);
    *(u16*)&hlds[cur^1][r][w*32 + uu0] = (u16)pk;
    u32 hb;
    asm("v_cvt_pk_bf16_f32 %0, %1, %2" : "=v"(hb) : "v"(h0), "v"(h1));
    hb = (t_src < slr) ? hb : 0u;
    *(u32*)(hptr + hoff) = hb;
    __syncthreads();
    cur ^= 1;
    xptr += 16384;
    hptr += hstep;
    t_src += ts_inc;
  }
}

// ---------------- generic MFMA GEMM (A row-major bf16, B frag-packed) ----------------
__global__ __launch_bounds__(256) void gemm_frag(
    const u16* __restrict__ A, const u16* __restrict__ Bf,
    int N, int K, int mode,
    const float* __restrict__ bias0, const float* __restrict__ bias1,
    u16* __restrict__ out, const u16* __restrict__ hid){
  const int tid = threadIdx.x;
  const int l = tid & 63, w = tid >> 6;
  const int row0 = blockIdx.x*64 + w*16;
  const int col0 = blockIdx.y*128;
  const int Nt16 = N>>4;
  f32x4 acc[8];
  f32x4 zf4 = {0.f,0.f,0.f,0.f};
  #pragma unroll
  for (int i=0;i<8;i++) acc[i]=zf4;
  const int rl = row0 + (l&15);
  const int kb = ((l>>4)&3)*8;
  const int nK = K>>5;
  for (int ks=0; ks<nK; ++ks){
    int kc = ks*32 + kb;
    short8 a;
    if (mode==1){
      int b = rl>>9, t = rl&511;
      if (kc < 512){
        if (t==0){ short8 z8={0,0,0,0,0,0,0,0}; a=z8; }
        else a = *(const short8*)(hid + ((size_t)(b*512 + t-1)*512 + kc));
      } else {
        a = *(const short8*)(hid + ((size_t)(b*512 + t)*512 + (kc-512)));
      }
    } else {
      a = *(const short8*)(A + ((size_t)rl*K + kc));
    }
    const short8* bp = (const short8*)Bf + ((size_t)ks*Nt16 + (col0>>4))*64 + l;
    #pragma unroll
    for (int n=0;n<8;n++){
      short8 b8 = bp[n*64];
      acc[n] = __builtin_amdgcn_mfma_f32_16x16x32_bf16(a, b8, acc[n], 0,0,0);
    }
  }
  // mode 0: gate scale (exp2-domain pre-scale); c1&3 == l&3 (thread-constant)
  float scg = ((l&3)==2) ? (2.f*LOG2E) : (-LOG2E);
  #pragma unroll
  for (int n=0;n<8;n++){
    int col = col0 + n*16 + (l&15);
    #pragma unroll
    for (int q=0;q<4;q++){
      int row = row0 + ((l>>4)&3)*4 + q;
      float v = acc[n][q];
      if (mode==0){
        int d = col>>10, c1 = col&1023;
        v = (v + (d ? bias1 : bias0)[(c1&3)*256 + (c1>>2)]) * scg;
        int b = row>>9, t = row&511;
        int t2 = d ? (511-t) : t;
        out[((size_t)(d*512 + t2)*16 + b)*1024 + c1] = f2bf(v);
      } else if (mode==1){
        v += (col<512)? bias0[col] : bias1[col-512];
        v = fmaxf(v, 0.f);
        out[(size_t)row*1024 + col] = f2bf(v);
      } else {
        out[(size_t)row*1024 + col] = f2bf(v);
      }
    }
  }
}

// ---------------- ll/lr ----------------
__global__ __launch_bounds__(256) void lin_kernel(const u16* __restrict__ flfr,
    const float* __restrict__ lw, const float* __restrict__ lb,
    const float* __restrict__ rw, const float* __restrict__ rb,
    float* __restrict__ llr){
  int row = blockIdx.x*4 + (threadIdx.x>>6);
  int l = threadIdx.x&63;
  const u16* fr = flfr + (size_t)row*1024;
  float pl=0.f, pr=0.f;
  #pragma unroll
  for (int j=0;j<8;j++){
    int ci = l*8+j;
    pl += bf2f(fr[ci]) * lw[ci];
    pr += bf2f(fr[512+ci]) * rw[ci];
  }
  #pragma unroll
  for (int off=32; off; off>>=1){ pl += __shfl_xor(pl, off, 64); pr += __shfl_xor(pr, off, 64); }
  if (l==0){ llr[row] = pl + lb[0]; llr[8192+row] = pr + rb[0]; }
}

// ---------------- banded bilinear + softmax ----------------
__global__ __launch_bounds__(256) void band_softmax(
  const u16* __restrict__ ulur, const u16* __restrict__ flfr,
  const float* __restrict__ llr, float* __restrict__ outp){
  int row = blockIdx.x*4 + (threadIdx.x>>6);
  int l = threadIdx.x&63;
  int b = row>>9, i = row&511;
  float ul[8], ur[8];
  const u16* up = ulur + (size_t)row*1024;
  #pragma unroll
  for (int j=0;j<8;j++){ ul[j]=bf2f(up[l*8+j]); ur[j]=bf2f(up[512+l*8+j]); }
  float sL = -1e30f, sR = -1e30f;
  for (int idx=0; idx<16; ++idx){
    int jL = i - idx;
    float p = 0.f;
    if (jL >= 0){
      const u16* f = flfr + (size_t)(b*512+jL)*1024;
      #pragma unroll
      for (int j=0;j<8;j++) p += ul[j]*bf2f(f[l*8+j]);
    }
    #pragma unroll
    for (int off=32; off; off>>=1) p += __shfl_xor(p, off, 64);
    if (l==idx && jL>=0) sL = p + llr[b*512+jL];
    int jR = i + idx;
    float pr_ = 0.f;
    if (jR < 512){
      const u16* f = flfr + (size_t)(b*512+jR)*1024;
      #pragma unroll
      for (int j=0;j<8;j++) pr_ += ur[j]*bf2f(f[512+l*8+j]);
    }
    #pragma unroll
    for (int off=32; off; off>>=1) pr_ += __shfl_xor(pr_, off, 64);
    if (l==idx && jR<512) sR = pr_ + llr[8192+b*512+jR];
  }
  float mL = sL, mR = sR;
  #pragma unroll
  for (int off=8; off; off>>=1){ mL = fmaxf(mL, __shfl_xor(mL, off, 16)); mR = fmaxf(mR, __shfl_xor(mR, off, 16)); }
  float eL = (sL>-1e29f)? __expf(sL-mL) : 0.f;
  float eR = (sR>-1e29f)? __expf(sR-mR) : 0.f;
  float suL = eL, suR = eR;
  #pragma unroll
  for (int off=8; off; off>>=1){ suL += __shfl_xor(suL, off, 16); suR += __shfl_xor(suR, off, 16); }
  float pL = eL/suL, pR = eR/suR;
  size_t obase = ((size_t)b*512 + i)*512;
  float vl[8], vr[8];
  #pragma unroll
  for (int j=0;j<8;j++){
    int ci = l*8+j;
    int ixl = i - ci;
    float v1 = __shfl(pL, ixl & 15, 64);
    vl[j] = (ixl>=0 && ixl<16) ? v1 : 0.f;
    int ixr = ci - i;
    float v2 = __shfl(pR, ixr & 15, 64);
    vr[j] = (ixr>=0 && ixr<16) ? v2 : 0.f;
  }
  float4* oL = (float4*)(outp + obase + l*8);
  oL[0] = make_float4(vl[0],vl[1],vl[2],vl[3]);
  oL[1] = make_float4(vl[4],vl[5],vl[6],vl[7]);
  float4* oR = (float4*)(outp + (size_t)16*512*512 + obase + l*8);
  oR[0] = make_float4(vr[0],vr[1],vr[2],vr[3]);
  oR[1] = make_float4(vr[4],vr[5],vr[6],vr[7]);
}

// ---------------- host launch ----------------
extern "C" void kernel_launch(void* const* d_in, const int* in_sizes, int n_in,
                              void* d_out, int out_size, void* d_ws, size_t ws_size,
                              hipStream_t stream) {
  const int* words    = (const int*)d_in[0];
  const int* poss     = (const int*)d_in[1];
  const int* seq_len  = (const int*)d_in[2];
  const int* chars    = (const int*)d_in[3];
  const int* char_len = (const int*)d_in[4];
  const float* word_emb = (const float*)d_in[6];
  const float* pos_emb  = (const float*)d_in[7];
  const float* char_emb = (const float*)d_in[8];
  const float* cWi = (const float*)d_in[9];
  const float* cWh = (const float*)d_in[10];
  const float* cb  = (const float*)d_in[11];
  const float* fWi = (const float*)d_in[12];
  const float* fWh = (const float*)d_in[13];
  const float* fb  = (const float*)d_in[14];
  const float* bWi = (const float*)d_in[15];
  const float* bWh = (const float*)d_in[16];
  const float* bb  = (const float*)d_in[17];
  const float* convL_k = (const float*)d_in[18];
  const float* convL_b = (const float*)d_in[19];
  const float* convR_k = (const float*)d_in[20];
  const float* convR_b = (const float*)d_in[21];
  const float* bilinL  = (const float*)d_in[22];
  const float* bilinR  = (const float*)d_in[23];
  const float* linL_w  = (const float*)d_in[24];
  const float* linL_b  = (const float*)d_in[25];
  const float* linR_w  = (const float*)d_in[26];
  const float* linR_b  = (const float*)d_in[27];

  char* ws = (char*)d_ws;
  constexpr size_t OFF_WHQ = 0;
  constexpr size_t OFF_WHC = OFF_WHQ + 524288;
  constexpr size_t OFF_WIF = OFF_WHC + 131072;
  constexpr size_t OFF_CVF = OFF_WIF + 2097152;
  constexpr size_t OFF_BLF = OFF_CVF + 2097152;
  constexpr size_t OFF_CGT = OFF_BLF + 1048576;
  constexpr size_t OFF_XPD = OFF_CGT + 262144;
  constexpr size_t OFF_XMN = OFF_XPD + 8388608;
  constexpr size_t OFF_HID = OFF_XMN + 33554432;
  constexpr size_t OFF_FLR = OFF_HID + 8388608;
  constexpr size_t OFF_ULR = OFF_FLR + 16777216;
  constexpr size_t OFF_LLR = OFF_ULR + 16777216;

  pack_whq<<<1024,64,0,stream>>>(fWh,bWh,(u64*)(ws+OFF_WHQ));
  pack_whc<<<128,64,0,stream>>>(cWh,(u16*)(ws+OFF_WHC));
  pack_bfrag<<<2048,64,0,stream>>>(fWi,bWi,(u16*)(ws+OFF_WIF),2048,512,0);
  pack_bfrag<<<2048,64,0,stream>>>(convL_k,convR_k,(u16*)(ws+OFF_CVF),1024,1024,1);
  pack_bfrag<<<1024,64,0,stream>>>(bilinL,bilinR,(u16*)(ws+OFF_BLF),1024,512,2);
  prep_cgate<<<128,256,0,stream>>>(char_emb,cWi,cb,(float*)(ws+OFF_CGT));
  embed_gather<<<8192,128,0,stream>>>(words,poss,word_emb,pos_emb,(u16*)(ws+OFF_XPD));
  char_lstm<<<512,512,0,stream>>>((const u16*)(ws+OFF_WHC),(const float*)(ws+OFF_CGT),
                                  chars,char_len,(u16*)(ws+OFF_XPD));
  gemm_frag<<<dim3(128,16),256,0,stream>>>((const u16*)(ws+OFF_XPD),(const u16*)(ws+OFF_WIF),
                                  2048,512,0,fb,bb,(u16*)(ws+OFF_XMN),nullptr);
  main_lstm<<<8,512,0,stream>>>((const u64*)(ws+OFF_WHQ),(const u16*)(ws+OFF_XMN),
                                  seq_len,(u16*)(ws+OFF_HID));
  gemm_frag<<<dim3(128,8),256,0,stream>>>(nullptr,(const u16*)(ws+OFF_CVF),
                                  1024,1024,1,convL_b,convR_b,(u16*)(ws+OFF_FLR),(const u16*)(ws+OFF_HID));
  gemm_frag<<<dim3(128,8),256,0,stream>>>((const u16*)(ws+OFF_HID),(const u16*)(ws+OFF_BLF),
                                  1024,512,2,convL_b,convR_b,(u16*)(ws+OFF_ULR),nullptr);
  lin_kernel<<<2048,256,0,stream>>>((const u16*)(ws+OFF_FLR),linL_w,linL_b,linR_w,linR_b,
                                  (float*)(ws+OFF_LLR));
  band_softmax<<<2048,256,0,stream>>>((const u16*)(ws+OFF_ULR),(const u16*)(ws+OFF_FLR),
                                  (const float*)(ws+OFF_LLR),(float*)d_out);
}

// Round 8
// 1078.615 us; speedup vs baseline: 2.6831x; 1.2528x over previous
//
#include <hip/hip_runtime.h>

typedef unsigned short u16;
typedef unsigned int   u32;
typedef unsigned long long u64;
typedef __attribute__((ext_vector_type(8))) short short8;
typedef __attribute__((ext_vector_type(4))) float f32x4;
typedef __attribute__((ext_vector_type(4))) int   i32x4;

#define DEV static __device__ __forceinline__

#define LOG2E 1.44269504f
#define DSCN (-LOG2E/(127.f*900.f))
#define DSCG (2.f*LOG2E/(127.f*900.f))

DEV float bf2f(u16 u){ return __uint_as_float(((u32)u)<<16); }
DEV u16 f2bf(float f){ u32 u=__float_as_uint(f); return (u16)((u + 0x7FFFu + ((u>>16)&1u))>>16); }
DEV float sigf(float x){ return 1.f/(1.f+__expf(-x)); }
DEV float tanhfast(float x){ return 2.f*sigf(2.f*x)-1.f; }

// raw-rate transcendentals
DEV float ex2(float x){ float r; asm("v_exp_f32 %0, %1" : "=v"(r) : "v"(x)); return r; }
DEV float rcpf_(float x){ float r; asm("v_rcp_f32 %0, %1" : "=v"(r) : "v"(x)); return r; }
// zp = -1.4427*z  ->  sigmoid(z)
DEV float sig2(float zp){ return rcpf_(1.f + ex2(zp)); }
// gp = 2.8854*g  ->  tanh(g)
DEV float tanh2(float gp){ float e = ex2(gp); return (e-1.f)*rcpf_(e+1.f); }

// zlds bank swizzle: bijective, keeps 16B alignment, evens/odds stay disjoint sets
DEV int zswz(int row){ return row ^ ((row>>3)&3); }

// ---------------- prep kernels ----------------

__global__ void prep_cgate(const float* __restrict__ emb, const float* __restrict__ cWi,
                           const float* __restrict__ cb, float* __restrict__ tab){
  int c = blockIdx.x;
  for (int g = threadIdx.x; g < 512; g += 256){
    float sacc = cb[g];
    for (int k=0;k<64;k++) sacc += emb[c*64+k]*cWi[k*512+g];
    tab[c*512+g]=sacc;
  }
}

// pack main-LSTM recurrent weights int8 (x900), frag-major for 16x16x64 i8 MFMA:
// [dir][w8][tt8][ks4][lane64] 16 bytes. tt = gate*2 + parity;
// col = gate*256 + w*32 + 2*(l&15) + parity ; k = ks*64 + (l>>4)*16 + byte_j
__global__ void pack_whq(const float* __restrict__ fWh, const float* __restrict__ bWh,
                         i32x4* __restrict__ whq){
  int blk = blockIdx.x;            // 512
  int l = threadIdx.x;             // 64
  int ks = blk&3, tt=(blk>>2)&7, w=(blk>>5)&7, dir=blk>>8;
  const float* W = dir? bWh : fWh;
  int gate = tt>>1;
  int col = gate*256 + w*32 + 2*(l&15) + (tt&1);
  int kb = ks*64 + (l>>4)*16;
  u32 words[4];
  for (int wi=0; wi<4; wi++){
    u32 v = 0;
    for (int j=0;j<4;j++){
      int k = kb + wi*4 + j;
      int q = (int)rintf(W[(size_t)k*1024+col]*900.f);
      q = q>127?127:(q<-127?-127:q);
      v |= ((u32)(q & 0xFF)) << (8*j);
    }
    words[wi]=v;
  }
  i32x4 out; out.x=(int)words[0]; out.y=(int)words[1]; out.z=(int)words[2]; out.w=(int)words[3];
  whq[(size_t)blk*64 + l] = out;
}

// pack char-LSTM recurrent weights bf16, frag-major: [w8][tt4][ks4][lane64] 8xbf16
__global__ void pack_whc(const float* __restrict__ cWh, u16* __restrict__ whc){
  int blk=blockIdx.x;              // 128
  int l=threadIdx.x;
  int ks=blk&3, tt=(blk>>2)&3, w=blk>>4;
  int col = 128*tt + 16*w + (l&15);
  u16 vals[8];
  for (int j=0;j<8;j++){
    int k = ks*32 + ((l>>4)&3)*8 + j;
    vals[j] = f2bf(cWh[(size_t)k*512+col]);
  }
  *((uint4*)whc + (size_t)blk*64 + l) = *(uint4*)vals;
}

// generic bf16 B-fragment pack: dst[(ks*(N/16)+n)*64+l] = 8 bf16 (k-consecutive)
// mode 0: Wi concat (fWi|bWi), K=512 (pad from 492), cols gate-interleaved: c1=u*4+gate
// mode 1: conv taps; mode 2: bilin concat
__global__ void pack_bfrag(const float* __restrict__ S0, const float* __restrict__ S1,
                           u16* __restrict__ dst, int N, int K, int mode){
  int blk = blockIdx.x; int l = threadIdx.x;
  int Nt = N>>4;
  int ks = blk / Nt, n = blk % Nt;
  int col = n*16 + (l&15);
  u16 vals[8];
  for (int j=0;j<8;j++){
    int k = ks*32 + ((l>>4)&3)*8 + j;
    float v;
    if (mode==0){
      int d = col>>10, c1 = col&1023;
      int srccol = (c1&3)*256 + (c1>>2);
      v = (k<492) ? (d ? S1[(size_t)k*1024+srccol] : S0[(size_t)k*1024+srccol]) : 0.f;
    } else if (mode==1){
      int tap=k>>9, kk=k&511;
      v = (col<512) ? S0[((size_t)tap*512+kk)*512+col] : S1[((size_t)tap*512+kk)*512+col-512];
    } else {
      v = (col<512) ? S0[(size_t)k*512+col] : S1[(size_t)k*512+col-512];
    }
    vals[j]=f2bf(v);
  }
  *((uint4*)dst + (size_t)blk*64 + l) = *(uint4*)vals;
}

// word/pos embedding gather into xpad[8192][512] bf16
__global__ void embed_gather(const int* __restrict__ words, const int* __restrict__ poss,
                             const float* __restrict__ wemb, const float* __restrict__ pemb,
                             u16* __restrict__ xpad){
  int row = blockIdx.x; int tid = threadIdx.x;   // 128 threads
  int wd = words[row], ps = poss[row];
  const float* wsrc = wemb + (size_t)wd*300;
  u16* xr = xpad + (size_t)row*512;
  for (int i=tid;i<300;i+=128) xr[i] = f2bf(wsrc[i]);
  if (tid<64) xr[300+tid] = f2bf(pemb[(size_t)ps*64+tid]);
  if (tid>=108) xr[492 + (tid-108)] = 0;
}

// ---------------- char LSTM ----------------
__global__ __launch_bounds__(512) void char_lstm(
  const u16* __restrict__ whcf, const float* __restrict__ cgate,
  const int* __restrict__ chars, const int* __restrict__ char_len,
  u16* __restrict__ xpad){
  const int tid = threadIdx.x; const int l = tid&63, w = tid>>6;
  const int rbase = blockIdx.x*16;
  __shared__ u16 hlds[16][136];
  __shared__ int chs[16][16];
  __shared__ int cidx[16];
  for (int i = tid; i < 16*136; i += 512) ((u16*)hlds)[i] = 0;
  if (tid < 256) chs[tid>>4][tid&15] = chars[(size_t)(rbase + (tid>>4))*16 + (tid&15)];
  if (tid < 16){ int cl = char_len[rbase+tid]-1; cidx[tid] = cl<0?0:(cl>15?15:cl); }
  short8 bq[4][4];
  #pragma unroll
  for (int tt=0;tt<4;tt++)
    #pragma unroll
    for(int ks=0;ks<4;ks++)
      bq[tt][ks] = *((const short8*)whcf + (((w*4+tt)*4+ks)*64 + l));
  float c[4] = {0.f,0.f,0.f,0.f};
  const int u = w*16 + (l&15);
  __syncthreads();
  for (int s=0;s<16;s++){
    short8 a[4];
    #pragma unroll
    for (int ks=0;ks<4;ks++)
      a[ks] = *(const short8*)&hlds[l&15][ks*32 + ((l>>4)&3)*8];
    f32x4 acc[4];
    f32x4 zf4 = {0.f,0.f,0.f,0.f};
    #pragma unroll
    for (int tt=0;tt<4;tt++) acc[tt]=zf4;
    #pragma unroll
    for (int tt=0;tt<4;tt++)
      #pragma unroll
      for (int ks=0;ks<4;ks++)
        acc[tt] = __builtin_amdgcn_mfma_f32_16x16x32_bf16(a[ks], bq[tt][ks], acc[tt],0,0,0);
    float hv[4];
    #pragma unroll
    for (int q=0;q<4;q++){
      int r = ((l>>4)&3)*4 + q;
      int ch = chs[r][s];
      const float* tb = cgate + (size_t)ch*512 + u;
      float zi = tb[0]   + acc[0][q];
      float zf = tb[128] + acc[1][q];
      float zg = tb[256] + acc[2][q];
      float zo = tb[384] + acc[3][q];
      float cn = sigf(zf)*c[q] + sigf(zi)*tanhfast(zg);
      c[q] = cn;
      hv[q] = sigf(zo)*tanhfast(cn);
    }
    __syncthreads();
    #pragma unroll
    for (int q=0;q<4;q++){
      int r = ((l>>4)&3)*4 + q;
      u16 hb = f2bf(hv[q]);
      hlds[r][u] = hb;
      if (s == cidx[r]) xpad[(size_t)(rbase + r)*512 + 364 + u] = hb;
    }
    __syncthreads();
  }
}

// ---------------- main LSTM (fwd/bwd), 4 WGs per direction (batch-split) ----------------
// grid=8 x 512 thr. int8 register-resident Wh (asm-pinned), K=64 i8 MFMA (2x fp8 rate).
// Even tiles -> write zE -> odd-tile MFMAs -> h0 gates (overlap) -> write zO -> h1 gates.
// zlds rows XOR-swizzled (<=2-way banks). acc seeded from loop-invariant zero4 (no movs).
__global__ __launch_bounds__(512,2) void main_lstm(
  const i32x4* __restrict__ whq, const u16* __restrict__ xmain,
  const int* __restrict__ seq_len, u16* __restrict__ hidden){
  const int wg = blockIdx.x;
  const int dir = wg>>2, rb4 = (wg&3)*4;
  const int tid = threadIdx.x; const int l = tid&63, w = tid>>6;
  const int l16 = l&15, kq = l>>4;
  const int r = l&3, uu0 = (l>>2)*2;
  __shared__ signed char hlds[2][16][272];   // i8 h (x127); rows 4-15 stay zero
  __shared__ float zlds[8][128][4];          // per-wave private, XOR-swizzled rows
  for (int i=tid; i<2*16*272; i+=512) ((char*)&hlds[0][0][0])[i]=0;
  const int slr = seq_len[rb4 + r];
  i32x4 bq[8][4];
  #pragma unroll
  for (int tt=0;tt<8;tt++)
    #pragma unroll
    for(int ks=0;ks<4;ks++){
      bq[tt][ks] = whq[ (((size_t)(dir*8+w)*8+tt)*4+ks)*64 + l ];
      asm volatile("" : "+v"(bq[tt][ks]));   // pin: no remat/sink into the loop
    }
  float c0 = 0.f, c1 = 0.f;
  const int xoff = (rb4 + r)*1024 + (w*32 + uu0)*4;            // [t][r][u][gate]
  const int hoff = (rb4 + r)*262144 + dir*256 + (w*32 + uu0);  // [b][t][512]
  // thread-constant swizzled z read rows
  const int rei = zswz(uu0),      ref_ = zswz(32+uu0),  reg_ = zswz(64+uu0),  reo = zswz(96+uu0);
  const int roi = zswz(uu0+1),    rof = zswz(32+uu0+1), rog = zswz(64+uu0+1), roo = zswz(96+uu0+1);
  const u16* xptr = xmain + (size_t)dir*8388608;
  u16* hptr = hidden + (size_t)(dir?511:0)*512;
  const int hstep = dir? -512 : 512;
  int t_src = dir? 511 : 0;
  const int ts_inc = dir? -1 : 1;
  int cur = 0;
  i32x4 zero4 = {0,0,0,0};
  asm volatile("" : "+v"(zero4));            // keep zero tuple live outside the loop
  __syncthreads();
  #pragma unroll 1
  for (int t=0;t<512;t++){
    // X load first (consumed last) — latency hides under MFMA
    uint4 xv = *(const uint4*)(xptr + xoff);
    i32x4 a[4];
    #pragma unroll
    for (int ks=0;ks<4;ks++)
      a[ks] = *(const i32x4*)&hlds[cur][l16][ks*64 + kq*16];
    // even tiles (units u0)
    i32x4 accE[4], accO[4];
    #pragma unroll
    for (int g=0; g<4; g++)
      accE[g] = __builtin_amdgcn_mfma_i32_16x16x64_i8(a[0], bq[g*2][0], zero4, 0,0,0);
    #pragma unroll
    for (int ks=1; ks<4; ks++)
      #pragma unroll
      for (int g=0; g<4; g++)
        accE[g] = __builtin_amdgcn_mfma_i32_16x16x64_i8(a[ks], bq[g*2][ks], accE[g], 0,0,0);
    if (l < 16){
      #pragma unroll
      for (int g=0; g<4; g++)
        *(i32x4*)&zlds[w][zswz(g*32 + 2*l16)][0] = accE[g];
    }
    // odd tiles (units u0+1) — pipe drains while h0 gates run below
    #pragma unroll
    for (int g=0; g<4; g++)
      accO[g] = __builtin_amdgcn_mfma_i32_16x16x64_i8(a[0], bq[g*2+1][0], zero4, 0,0,0);
    #pragma unroll
    for (int ks=1; ks<4; ks++)
      #pragma unroll
      for (int g=0; g<4; g++)
        accO[g] = __builtin_amdgcn_mfma_i32_16x16x64_i8(a[ks], bq[g*2+1][ks], accO[g], 0,0,0);
    // h0 gates from even z
    int zei = *(const int*)&zlds[w][rei ][r];
    int zef = *(const int*)&zlds[w][ref_][r];
    int zeg = *(const int*)&zlds[w][reg_][r];
    int zeo = *(const int*)&zlds[w][reo ][r];
    float zi0 = fmaf((float)zei, DSCN, __uint_as_float(xv.x<<16));
    float zf0 = fmaf((float)zef, DSCN, __uint_as_float(xv.x&0xFFFF0000u));
    float zg0 = fmaf((float)zeg, DSCG, __uint_as_float(xv.y<<16));
    float zo0 = fmaf((float)zeo, DSCN, __uint_as_float(xv.y&0xFFFF0000u));
    float si0 = sig2(zi0), sf0 = sig2(zf0), so0 = sig2(zo0), tg0 = tanh2(zg0);
    float cn0 = sf0*c0 + si0*tg0; c0 = cn0;
    float h0 = so0 * tanh2(cn0*(2.f*LOG2E));
    // odd z out, h1 gates
    if (l < 16){
      #pragma unroll
      for (int g=0; g<4; g++)
        *(i32x4*)&zlds[w][zswz(g*32 + 2*l16 + 1)][0] = accO[g];
    }
    int zoi = *(const int*)&zlds[w][roi][r];
    int zof = *(const int*)&zlds[w][rof][r];
    int zog = *(const int*)&zlds[w][rog][r];
    int zoo = *(const int*)&zlds[w][roo][r];
    float zi1 = fmaf((float)zoi, DSCN, __uint_as_float(xv.z<<16));
    float zf1 = fmaf((float)zof, DSCN, __uint_as_float(xv.z&0xFFFF0000u));
    float zg1 = fmaf((float)zog, DSCG, __uint_as_float(xv.w<<16));
    float zo1 = fmaf((float)zoo, DSCN, __uint_as_float(xv.w&0xFFFF0000u));
    float si1 = sig2(zi1), sf1 = sig2(zf1), so1 = sig2(zo1), tg1 = tanh2(zg1);
    float cn1 = sf1*c1 + si1*tg1; c1 = cn1;
    float h1 = so1 * tanh2(cn1*(2.f*LOG2E));
    // h stores: int8 pair -> LDS, bf16 pair -> global
    int q0 = (int)rintf(h0*127.f), q1 = (int)rintf(h1*127.f);
    *(u16*)&hlds[cur^1][r][w*32 + uu0] = (u16)((q0&0xFF) | ((q1&0xFF)<<8));
    u32 hb;
    asm("v_cvt_pk_bf16_f32 %0, %1, %2" : "=v"(hb) : "v"(h0), "v"(h1));
    hb = (t_src < slr) ? hb : 0u;
    *(u32*)(hptr + hoff) = hb;
    __syncthreads();
    cur ^= 1;
    xptr += 16384;
    hptr += hstep;
    t_src += ts_inc;
  }
}

// ---------------- generic MFMA GEMM (A row-major bf16, B frag-packed) ----------------
__global__ __launch_bounds__(256) void gemm_frag(
    const u16* __restrict__ A, const u16* __restrict__ Bf,
    int N, int K, int mode,
    const float* __restrict__ bias0, const float* __restrict__ bias1,
    u16* __restrict__ out, const u16* __restrict__ hid){
  const int tid = threadIdx.x;
  const int l = tid & 63, w = tid >> 6;
  const int row0 = blockIdx.x*64 + w*16;
  const int col0 = blockIdx.y*128;
  const int Nt16 = N>>4;
  f32x4 acc[8];
  f32x4 zf4 = {0.f,0.f,0.f,0.f};
  #pragma unroll
  for (int i=0;i<8;i++) acc[i]=zf4;
  const int rl = row0 + (l&15);
  const int kb = ((l>>4)&3)*8;
  const int nK = K>>5;
  for (int ks=0; ks<nK; ++ks){
    int kc = ks*32 + kb;
    short8 a;
    if (mode==1){
      int b = rl>>9, t = rl&511;
      if (kc < 512){
        if (t==0){ short8 z8={0,0,0,0,0,0,0,0}; a=z8; }
        else a = *(const short8*)(hid + ((size_t)(b*512 + t-1)*512 + kc));
      } else {
        a = *(const short8*)(hid + ((size_t)(b*512 + t)*512 + (kc-512)));
      }
    } else {
      a = *(const short8*)(A + ((size_t)rl*K + kc));
    }
    const short8* bp = (const short8*)Bf + ((size_t)ks*Nt16 + (col0>>4))*64 + l;
    #pragma unroll
    for (int n=0;n<8;n++){
      short8 b8 = bp[n*64];
      acc[n] = __builtin_amdgcn_mfma_f32_16x16x32_bf16(a, b8, acc[n], 0,0,0);
    }
  }
  // mode 0: gate scale (exp2-domain pre-scale); c1&3 == l&3 (thread-constant)
  float scg = ((l&3)==2) ? (2.f*LOG2E) : (-LOG2E);
  #pragma unroll
  for (int n=0;n<8;n++){
    int col = col0 + n*16 + (l&15);
    #pragma unroll
    for (int q=0;q<4;q++){
      int row = row0 + ((l>>4)&3)*4 + q;
      float v = acc[n][q];
      if (mode==0){
        int d = col>>10, c1 = col&1023;
        v = (v + (d ? bias1 : bias0)[(c1&3)*256 + (c1>>2)]) * scg;
        int b = row>>9, t = row&511;
        int t2 = d ? (511-t) : t;
        out[((size_t)(d*512 + t2)*16 + b)*1024 + c1] = f2bf(v);
      } else if (mode==1){
        v += (col<512)? bias0[col] : bias1[col-512];
        v = fmaxf(v, 0.f);
        out[(size_t)row*1024 + col] = f2bf(v);
      } else {
        out[(size_t)row*1024 + col] = f2bf(v);
      }
    }
  }
}

// ---------------- ll/lr ----------------
__global__ __launch_bounds__(256) void lin_kernel(const u16* __restrict__ flfr,
    const float* __restrict__ lw, const float* __restrict__ lb,
    const float* __restrict__ rw, const float* __restrict__ rb,
    float* __restrict__ llr){
  int row = blockIdx.x*4 + (threadIdx.x>>6);
  int l = threadIdx.x&63;
  const u16* fr = flfr + (size_t)row*1024;
  float pl=0.f, pr=0.f;
  #pragma unroll
  for (int j=0;j<8;j++){
    int ci = l*8+j;
    pl += bf2f(fr[ci]) * lw[ci];
    pr += bf2f(fr[512+ci]) * rw[ci];
  }
  #pragma unroll
  for (int off=32; off; off>>=1){ pl += __shfl_xor(pl, off, 64); pr += __shfl_xor(pr, off, 64); }
  if (l==0){ llr[row] = pl + lb[0]; llr[8192+row] = pr + rb[0]; }
}

// ---------------- banded bilinear + softmax ----------------
__global__ __launch_bounds__(256) void band_softmax(
  const u16* __restrict__ ulur, const u16* __restrict__ flfr,
  const float* __restrict__ llr, float* __restrict__ outp){
  int row = blockIdx.x*4 + (threadIdx.x>>6);
  int l = threadIdx.x&63;
  int b = row>>9, i = row&511;
  float ul[8], ur[8];
  const u16* up = ulur + (size_t)row*1024;
  #pragma unroll
  for (int j=0;j<8;j++){ ul[j]=bf2f(up[l*8+j]); ur[j]=bf2f(up[512+l*8+j]); }
  float sL = -1e30f, sR = -1e30f;
  for (int idx=0; idx<16; ++idx){
    int jL = i - idx;
    float p = 0.f;
    if (jL >= 0){
      const u16* f = flfr + (size_t)(b*512+jL)*1024;
      #pragma unroll
      for (int j=0;j<8;j++) p += ul[j]*bf2f(f[l*8+j]);
    }
    #pragma unroll
    for (int off=32; off; off>>=1) p += __shfl_xor(p, off, 64);
    if (l==idx && jL>=0) sL = p + llr[b*512+jL];
    int jR = i + idx;
    float pr_ = 0.f;
    if (jR < 512){
      const u16* f = flfr + (size_t)(b*512+jR)*1024;
      #pragma unroll
      for (int j=0;j<8;j++) pr_ += ur[j]*bf2f(f[512+l*8+j]);
    }
    #pragma unroll
    for (int off=32; off; off>>=1) pr_ += __shfl_xor(pr_, off, 64);
    if (l==idx && jR<512) sR = pr_ + llr[8192+b*512+jR];
  }
  float mL = sL, mR = sR;
  #pragma unroll
  for (int off=8; off; off>>=1){ mL = fmaxf(mL, __shfl_xor(mL, off, 16)); mR = fmaxf(mR, __shfl_xor(mR, off, 16)); }
  float eL = (sL>-1e29f)? __expf(sL-mL) : 0.f;
  float eR = (sR>-1e29f)? __expf(sR-mR) : 0.f;
  float suL = eL, suR = eR;
  #pragma unroll
  for (int off=8; off; off>>=1){ suL += __shfl_xor(suL, off, 16); suR += __shfl_xor(suR, off, 16); }
  float pL = eL/suL, pR = eR/suR;
  size_t obase = ((size_t)b*512 + i)*512;
  float vl[8], vr[8];
  #pragma unroll
  for (int j=0;j<8;j++){
    int ci = l*8+j;
    int ixl = i - ci;
    float v1 = __shfl(pL, ixl & 15, 64);
    vl[j] = (ixl>=0 && ixl<16) ? v1 : 0.f;
    int ixr = ci - i;
    float v2 = __shfl(pR, ixr & 15, 64);
    vr[j] = (ixr>=0 && ixr<16) ? v2 : 0.f;
  }
  float4* oL = (float4*)(outp + obase + l*8);
  oL[0] = make_float4(vl[0],vl[1],vl[2],vl[3]);
  oL[1] = make_float4(vl[4],vl[5],vl[6],vl[7]);
  float4* oR = (float4*)(outp + (size_t)16*512*512 + obase + l*8);
  oR[0] = make_float4(vr[0],vr[1],vr[2],vr[3]);
  oR[1] = make_float4(vr[4],vr[5],vr[6],vr[7]);
}

// ---------------- host launch ----------------
extern "C" void kernel_launch(void* const* d_in, const int* in_sizes, int n_in,
                              void* d_out, int out_size, void* d_ws, size_t ws_size,
                              hipStream_t stream) {
  const int* words    = (const int*)d_in[0];
  const int* poss     = (const int*)d_in[1];
  const int* seq_len  = (const int*)d_in[2];
  const int* chars    = (const int*)d_in[3];
  const int* char_len = (const int*)d_in[4];
  const float* word_emb = (const float*)d_in[6];
  const float* pos_emb  = (const float*)d_in[7];
  const float* char_emb = (const float*)d_in[8];
  const float* cWi = (const float*)d_in[9];
  const float* cWh = (const float*)d_in[10];
  const float* cb  = (const float*)d_in[11];
  const float* fWi = (const float*)d_in[12];
  const float* fWh = (const float*)d_in[13];
  const float* fb  = (const float*)d_in[14];
  const float* bWi = (const float*)d_in[15];
  const float* bWh = (const float*)d_in[16];
  const float* bb  = (const float*)d_in[17];
  const float* convL_k = (const float*)d_in[18];
  const float* convL_b = (const float*)d_in[19];
  const float* convR_k = (const float*)d_in[20];
  const float* convR_b = (const float*)d_in[21];
  const float* bilinL  = (const float*)d_in[22];
  const float* bilinR  = (const float*)d_in[23];
  const float* linL_w  = (const float*)d_in[24];
  const float* linL_b  = (const float*)d_in[25];
  const float* linR_w  = (const float*)d_in[26];
  const float* linR_b  = (const float*)d_in[27];

  char* ws = (char*)d_ws;
  constexpr size_t OFF_WHQ = 0;
  constexpr size_t OFF_WHC = OFF_WHQ + 524288;
  constexpr size_t OFF_WIF = OFF_WHC + 131072;
  constexpr size_t OFF_CVF = OFF_WIF + 2097152;
  constexpr size_t OFF_BLF = OFF_CVF + 2097152;
  constexpr size_t OFF_CGT = OFF_BLF + 1048576;
  constexpr size_t OFF_XPD = OFF_CGT + 262144;
  constexpr size_t OFF_XMN = OFF_XPD + 8388608;
  constexpr size_t OFF_HID = OFF_XMN + 33554432;
  constexpr size_t OFF_FLR = OFF_HID + 8388608;
  constexpr size_t OFF_ULR = OFF_FLR + 16777216;
  constexpr size_t OFF_LLR = OFF_ULR + 16777216;

  pack_whq<<<512,64,0,stream>>>(fWh,bWh,(i32x4*)(ws+OFF_WHQ));
  pack_whc<<<128,64,0,stream>>>(cWh,(u16*)(ws+OFF_WHC));
  pack_bfrag<<<2048,64,0,stream>>>(fWi,bWi,(u16*)(ws+OFF_WIF),2048,512,0);
  pack_bfrag<<<2048,64,0,stream>>>(convL_k,convR_k,(u16*)(ws+OFF_CVF),1024,1024,1);
  pack_bfrag<<<1024,64,0,stream>>>(bilinL,bilinR,(u16*)(ws+OFF_BLF),1024,512,2);
  prep_cgate<<<128,256,0,stream>>>(char_emb,cWi,cb,(float*)(ws+OFF_CGT));
  embed_gather<<<8192,128,0,stream>>>(words,poss,word_emb,pos_emb,(u16*)(ws+OFF_XPD));
  char_lstm<<<512,512,0,stream>>>((const u16*)(ws+OFF_WHC),(const float*)(ws+OFF_CGT),
                                  chars,char_len,(u16*)(ws+OFF_XPD));
  gemm_frag<<<dim3(128,16),256,0,stream>>>((const u16*)(ws+OFF_XPD),(const u16*)(ws+OFF_WIF),
                                  2048,512,0,fb,bb,(u16*)(ws+OFF_XMN),nullptr);
  main_lstm<<<8,512,0,stream>>>((const i32x4*)(ws+OFF_WHQ),(const u16*)(ws+OFF_XMN),
                                  seq_len,(u16*)(ws+OFF_HID));
  gemm_frag<<<dim3(128,8),256,0,stream>>>(nullptr,(const u16*)(ws+OFF_CVF),
                                  1024,1024,1,convL_b,convR_b,(u16*)(ws+OFF_FLR),(const u16*)(ws+OFF_HID));
  gemm_frag<<<dim3(128,8),256,0,stream>>>((const u16*)(ws+OFF_HID),(const u16*)(ws+OFF_BLF),
                                  1024,512,2,convL_b,convR_b,(u16*)(ws+OFF_ULR),nullptr);
  lin_kernel<<<2048,256,0,stream>>>((const u16*)(ws+OFF_FLR),linL_w,linL_b,linR_w,linR_b,
                                  (float*)(ws+OFF_LLR));
  band_softmax<<<2048,256,0,stream>>>((const u16*)(ws+OFF_ULR),(const u16*)(ws+OFF_FLR),
                                  (const float*)(ws+OFF_LLR),(float*)d_out);
}